// Round 5
// baseline (510.805 us; speedup 1.0000x reference)
//
#include <hip/hip_runtime.h>
#include <hip/hip_bf16.h>

#define D_MODEL 1024
#define NH 8
#define HD 128
#define BATCH 4
#define TSEQ 2048
#define MROWS (BATCH * TSEQ)  // 8192
#define QKV_LD 3072           // fused q|k|v row stride

typedef __attribute__((ext_vector_type(8))) __bf16 bf16x8;
typedef __attribute__((ext_vector_type(4))) __bf16 bf16x4;
typedef __attribute__((ext_vector_type(4))) float f32x4;
typedef __attribute__((ext_vector_type(8))) unsigned short u16x8;

#define SC2 0.1275174441680632f  // (1/sqrt(128)) * log2(e)

__device__ __forceinline__ void gload16(const void* g, void* lds) {
  __builtin_amdgcn_global_load_lds(
      (const __attribute__((address_space(1))) unsigned int*)g,
      (__attribute__((address_space(3))) unsigned int*)lds, 16, 0, 0);
}

// ---------------- small conversion / setup kernels ----------------
__global__ __launch_bounds__(256) void cvt_f32_to_bf16(const float* __restrict__ in,
                                                       __bf16* __restrict__ out, int n4) {
  int i = blockIdx.x * 256 + threadIdx.x;
  if (i < n4) {
    float4 v = reinterpret_cast<const float4*>(in)[i];
    bf16x4 o;
    o[0] = (__bf16)v.x; o[1] = (__bf16)v.y; o[2] = (__bf16)v.z; o[3] = (__bf16)v.w;
    reinterpret_cast<bf16x4*>(out)[i] = o;
  }
}

__global__ __launch_bounds__(256) void cvt4_weights(const float* __restrict__ w0,
                                                    const float* __restrict__ w1,
                                                    const float* __restrict__ w2,
                                                    const float* __restrict__ w3,
                                                    __bf16* __restrict__ out) {
  const int per = D_MODEL * D_MODEL / 4;
  int i = blockIdx.x * 256 + threadIdx.x;
  int m = i / per, j = i - m * per;
  const float* src = (m == 0) ? w0 : (m == 1) ? w1 : (m == 2) ? w2 : w3;
  float4 v = reinterpret_cast<const float4*>(src)[j];
  bf16x4 o;
  o[0] = (__bf16)v.x; o[1] = (__bf16)v.y; o[2] = (__bf16)v.z; o[3] = (__bf16)v.w;
  reinterpret_cast<bf16x4*>(out)[i] = o;
}

__global__ __launch_bounds__(256) void concat_bias(const float* __restrict__ a,
                                                   const float* __restrict__ b,
                                                   const float* __restrict__ c,
                                                   float* __restrict__ o) {
  int i = blockIdx.x * 256 + threadIdx.x;
  if (i < 3072) o[i] = (i < 1024) ? a[i] : (i < 2048) ? b[i - 1024] : c[i - 2048];
}

__global__ __launch_bounds__(256) void invert_lsum(float* __restrict__ L, int n) {
  int i = blockIdx.x * 256 + threadIdx.x;
  if (i < n) L[i] = 1.0f / (8.0f * L[i]);
}

// ---------------- generic 128x128 GEMM:  Y = A @ B^T (+bias), 2-phase dbuf ----
template <bool BF16OUT, bool CAUSAL, bool AFP32>
__global__ __launch_bounds__(256) void gemm128(const void* __restrict__ Aip,
                                               const __bf16* __restrict__ Bp,
                                               const float* __restrict__ bias,
                                               void* __restrict__ Yp, int K, int ldy,
                                               size_t sA, size_t sB, size_t sY) {
  __shared__ __bf16 As[2][128 * 32];
  __shared__ __bf16 Bs[2][128 * 32];
  const int tid = threadIdx.x;
  const int w = tid >> 6, l = tid & 63;
  const int lr = l & 15, lg = l >> 4;
  const int m0 = blockIdx.y * 128, n0 = blockIdx.x * 128;
  const int z = blockIdx.z;
  const __bf16* Ab = AFP32 ? nullptr : (const __bf16*)Aip + z * sA;
  const float* Af = AFP32 ? (const float*)Aip + z * sA : nullptr;
  const __bf16* Bb = Bp + z * sB;
  const int wm = w >> 1, wn = w & 1;
  f32x4 acc[4][4] = {};
  const int Klim = CAUSAL ? (m0 + 128 < K ? m0 + 128 : K) : K;
  const int nt = Klim >> 5;

  auto stage = [&](int t, int buf) {
    const int k0 = t << 5;
    if constexpr (!AFP32) {
#pragma unroll
      for (int i = 0; i < 2; ++i) {
        int s = w * 128 + i * 64 + l;
        int row = s >> 2, scp = s & 3;
        int sc = scp ^ ((row >> 1) & 3);
        gload16(Ab + (size_t)(m0 + row) * K + k0 + sc * 8, (char*)As[buf] + s * 16);
      }
    } else {
#pragma unroll
      for (int i = 0; i < 2; ++i) {
        int s = w * 128 + i * 64 + l;
        int row = s >> 2, sc = s & 3;
        const float* src = Af + (size_t)(m0 + row) * K + k0 + sc * 8;
        float4 lo = *reinterpret_cast<const float4*>(src);
        float4 hi = *reinterpret_cast<const float4*>(src + 4);
        bf16x8 v;
        v[0] = (__bf16)lo.x; v[1] = (__bf16)lo.y; v[2] = (__bf16)lo.z; v[3] = (__bf16)lo.w;
        v[4] = (__bf16)hi.x; v[5] = (__bf16)hi.y; v[6] = (__bf16)hi.z; v[7] = (__bf16)hi.w;
        int p = row * 4 + (sc ^ ((row >> 1) & 3));
        *reinterpret_cast<bf16x8*>((char*)As[buf] + p * 16) = v;
      }
    }
#pragma unroll
    for (int i = 0; i < 2; ++i) {
      int s = w * 128 + i * 64 + l;
      int row = s >> 2, scp = s & 3;
      int sc = scp ^ ((row >> 1) & 3);
      gload16(Bb + (size_t)(n0 + row) * K + k0 + sc * 8, (char*)Bs[buf] + s * 16);
    }
  };

  stage(0, 0);
  __syncthreads();
  int cur = 0;
  for (int t = 0; t < nt; ++t) {
    if (t + 1 < nt) stage(t + 1, cur ^ 1);
    bf16x8 af[4], bf[4];
#pragma unroll
    for (int f = 0; f < 4; ++f) {
      int ar = wm * 64 + f * 16 + lr;
      af[f] = *reinterpret_cast<const bf16x8*>((const char*)As[cur] + ar * 64 +
                                               ((lg ^ ((ar >> 1) & 3)) * 16));
      int br = wn * 64 + f * 16 + lr;
      bf[f] = *reinterpret_cast<const bf16x8*>((const char*)Bs[cur] + br * 64 +
                                               ((lg ^ ((br >> 1) & 3)) * 16));
    }
#pragma unroll
    for (int mf = 0; mf < 4; ++mf)
#pragma unroll
      for (int nf = 0; nf < 4; ++nf)
        acc[mf][nf] = __builtin_amdgcn_mfma_f32_16x16x32_bf16(af[mf], bf[nf], acc[mf][nf], 0, 0, 0);
    __syncthreads();
    cur ^= 1;
  }

#pragma unroll
  for (int mf = 0; mf < 4; ++mf) {
#pragma unroll
    for (int nf = 0; nf < 4; ++nf) {
#pragma unroll
      for (int r = 0; r < 4; ++r) {
        int grow = m0 + wm * 64 + mf * 16 + lg * 4 + r;
        int gcol = n0 + wn * 64 + nf * 16 + lr;
        float v = acc[mf][nf][r];
        if (bias) v += bias[gcol];
        if constexpr (BF16OUT)
          ((__bf16*)Yp + z * sY)[(size_t)grow * ldy + gcol] = (__bf16)v;
        else
          ((float*)Yp + z * sY)[(size_t)grow * ldy + gcol] = v;
      }
    }
  }
}

// ---------------- V[b][t][d] (ld=QKV_LD) -> Vt[b][d][t] ----------------
__global__ __launch_bounds__(256) void transpose_v(const __bf16* __restrict__ V,
                                                   __bf16* __restrict__ Vt) {
  __shared__ unsigned short tile[64 * 72];
  const int b = blockIdx.z;
  const int t0 = blockIdx.x * 64, d0 = blockIdx.y * 64;
  const int tid = threadIdx.x;
#pragma unroll
  for (int i = 0; i < 2; ++i) {
    int s = i * 256 + tid;
    int r = s >> 3, c8 = s & 7;
    u16x8 v = *reinterpret_cast<const u16x8*>(V + ((size_t)b * TSEQ + t0 + r) * QKV_LD + d0 + c8 * 8);
    *reinterpret_cast<u16x8*>(&tile[r * 72 + c8 * 8]) = v;
  }
  __syncthreads();
#pragma unroll
  for (int i = 0; i < 2; ++i) {
    int s = i * 256 + tid;
    int dr = s >> 3, t8 = s & 7;
    u16x8 o;
#pragma unroll
    for (int j = 0; j < 8; ++j) o[j] = tile[(t8 * 8 + j) * 72 + dr];
    *reinterpret_cast<u16x8*>(Vt + ((size_t)b * D_MODEL + d0 + dr) * TSEQ + t0 + t8 * 8) = o;
  }
}

// ---- [128][64] bf16 sliver staging, 256 threads; phys_seg = log_seg ^ (row&7)
__device__ __forceinline__ void stage64(const __bf16* __restrict__ src,
                                        __bf16* __restrict__ dst, int tid) {
#pragma unroll
  for (int i = 0; i < 4; ++i) {
    int s = i * 256 + tid;  // 1024 16B segs
    int row = s >> 3, sp = s & 7;
    int sl = sp ^ (row & 7);
    gload16(src + (size_t)row * QKV_LD + sl * 8, (char*)dst + s * 16);
  }
}

__device__ __forceinline__ bf16x8 ldfrag64(const __bf16* t, int row, int c, int lg) {
  return *reinterpret_cast<const bf16x8*>((const char*)t + row * 128 +
                                          (((c * 4 + lg) ^ (row & 7)) * 16));
}

// ---------------- attention core: 128x128 tile, 4 waves (64x64 each) --------
// k-dim = 16 slivers of 64 (8 heads x 2). MODE 0: Lsum atomics. MODE 1: alpha.
template <int MODE>
__global__ __launch_bounds__(256) void attn4w(const __bf16* __restrict__ QKV,
                                              const float* __restrict__ Linv,
                                              float* __restrict__ Out) {
  const int kt = blockIdx.x, qt = blockIdx.y, b = blockIdx.z;
  const int tid = threadIdx.x;
  const int q0 = qt * 128, k0 = kt * 128;
  if (kt > qt) {
    if (MODE == 1) {
      float4 zz = {0.f, 0.f, 0.f, 0.f};
#pragma unroll
      for (int i = 0; i < 16; ++i) {
        int s = i * 256 + tid;  // 4096 float4s
        int row = s >> 5, c = s & 31;
        *reinterpret_cast<float4*>(Out + ((size_t)(b * TSEQ) + q0 + row) * TSEQ + k0 + c * 4) = zz;
      }
    }
    return;
  }
  __shared__ __bf16 Qs[2][128 * 64];
  __shared__ __bf16 Ks[2][128 * 64];
  const int w = tid >> 6, l = tid & 63;
  const int lr = l & 15, lg = l >> 4;
  const int wq = w >> 1, wk = w & 1;  // 2x2 quadrants of 64x64
  const __bf16* qb0 = QKV + (size_t)(b * TSEQ + q0) * QKV_LD;         // Q cols base
  const __bf16* kb0 = QKV + (size_t)(b * TSEQ + k0) * QKV_LD + 1024;  // K cols base

  stage64(qb0, Qs[0], tid);
  stage64(kb0, Ks[0], tid);
  __syncthreads();

  f32x4 acc[4][4] = {};
  float outv[4][4][4] = {};
  float li[4][4];
  int cur = 0;
#pragma unroll 1
  for (int t = 0; t < 16; ++t) {
    if (t < 15) {
      stage64(qb0 + (t + 1) * 64, Qs[cur ^ 1], tid);
      stage64(kb0 + (t + 1) * 64, Ks[cur ^ 1], tid);
    }
    if (MODE == 1 && (t & 1) == 0) {
      // prefetch Linv for head t>>1
      int h = t >> 1;
#pragma unroll
      for (int mf = 0; mf < 4; ++mf) {
        float4 v = *reinterpret_cast<const float4*>(
            &Linv[((size_t)(b * NH + h)) * TSEQ + q0 + wq * 64 + mf * 16 + lg * 4]);
        li[mf][0] = v.x; li[mf][1] = v.y; li[mf][2] = v.z; li[mf][3] = v.w;
      }
    }
#pragma unroll
    for (int c = 0; c < 2; ++c) {
      bf16x8 af[4], bf[4];
#pragma unroll
      for (int f = 0; f < 4; ++f) {
        af[f] = ldfrag64(Qs[cur], wq * 64 + f * 16 + lr, c, lg);
        bf[f] = ldfrag64(Ks[cur], wk * 64 + f * 16 + lr, c, lg);
      }
#pragma unroll
      for (int mf = 0; mf < 4; ++mf)
#pragma unroll
        for (int nf = 0; nf < 4; ++nf)
          acc[mf][nf] = __builtin_amdgcn_mfma_f32_16x16x32_bf16(af[mf], bf[nf], acc[mf][nf], 0, 0, 0);
    }
    if (t & 1) {
      // epilogue for head h = t>>1 (registers only; overlaps next stage)
      const int h = t >> 1;
      const bool diag = (kt == qt);
      if constexpr (MODE == 0) {
        float ls[4][4] = {};
#pragma unroll
        for (int mf = 0; mf < 4; ++mf)
#pragma unroll
          for (int nf = 0; nf < 4; ++nf)
#pragma unroll
            for (int r = 0; r < 4; ++r) {
              int q = wq * 64 + mf * 16 + lg * 4 + r;
              int k = wk * 64 + nf * 16 + lr;
              if (!diag || k <= q) ls[mf][r] += exp2f(acc[mf][nf][r] * SC2);
              acc[mf][nf][r] = 0.f;
            }
#pragma unroll
        for (int m = 1; m < 16; m <<= 1)
#pragma unroll
          for (int mf = 0; mf < 4; ++mf)
#pragma unroll
            for (int r = 0; r < 4; ++r) ls[mf][r] += __shfl_xor(ls[mf][r], m, 64);
        if (lr == 0) {
#pragma unroll
          for (int mf = 0; mf < 4; ++mf)
#pragma unroll
            for (int r = 0; r < 4; ++r)
              atomicAdd(&Out[((size_t)(b * NH + h)) * TSEQ + q0 + wq * 64 + mf * 16 + lg * 4 + r],
                        ls[mf][r]);
        }
      } else {
#pragma unroll
        for (int mf = 0; mf < 4; ++mf)
#pragma unroll
          for (int nf = 0; nf < 4; ++nf)
#pragma unroll
            for (int r = 0; r < 4; ++r) {
              int q = wq * 64 + mf * 16 + lg * 4 + r;
              int k = wk * 64 + nf * 16 + lr;
              if (!diag || k <= q)
                outv[mf][nf][r] += exp2f(acc[mf][nf][r] * SC2) * li[mf][r];
              acc[mf][nf][r] = 0.f;
            }
      }
    }
    __syncthreads();
    cur ^= 1;
  }
  if constexpr (MODE == 1) {
#pragma unroll
    for (int mf = 0; mf < 4; ++mf)
#pragma unroll
      for (int nf = 0; nf < 4; ++nf)
#pragma unroll
        for (int r = 0; r < 4; ++r)
          Out[((size_t)(b * TSEQ) + q0 + wq * 64 + mf * 16 + lg * 4 + r) * TSEQ +
              k0 + wk * 64 + nf * 16 + lr] = outv[mf][nf][r];
  }
}

extern "C" void kernel_launch(void* const* d_in, const int* in_sizes, int n_in,
                              void* d_out, int out_size, void* d_ws, size_t ws_size,
                              hipStream_t stream) {
  const float* x  = (const float*)d_in[0];
  const float* Wq = (const float*)d_in[2];
  const float* bq = (const float*)d_in[3];
  const float* Wk = (const float*)d_in[4];
  const float* bk = (const float*)d_in[5];
  const float* Wv = (const float*)d_in[6];
  const float* bv = (const float*)d_in[7];
  const float* Wo = (const float*)d_in[8];
  const float* bo = (const float*)d_in[9];

  float* out_f = (float*)d_out;                    // [4,2048,1024]
  float* alpha = out_f + (size_t)MROWS * D_MODEL;  // [4,2048,2048]

  char* p = (char*)d_ws;
  __bf16* xb   = (__bf16*)p; p += (size_t)MROWS * D_MODEL * 2;      // reused as midb
  __bf16* wqb  = (__bf16*)p; p += (size_t)D_MODEL * D_MODEL * 2;    // wq|wk|wv|wo contiguous
  __bf16* wkb  = (__bf16*)p; p += (size_t)D_MODEL * D_MODEL * 2;
  __bf16* wvb  = (__bf16*)p; p += (size_t)D_MODEL * D_MODEL * 2;
  __bf16* wob  = (__bf16*)p; p += (size_t)D_MODEL * D_MODEL * 2;
  __bf16* qkv  = (__bf16*)p; p += (size_t)MROWS * QKV_LD * 2;       // 48 MB
  __bf16* vtb  = (__bf16*)p; p += (size_t)BATCH * D_MODEL * TSEQ * 2;
  float* lsum  = (float*)p;  p += (size_t)BATCH * NH * TSEQ * 4;
  float* bcat  = (float*)p;  p += 3072 * 4;
  __bf16* midb = xb;

  // 0) zero the atomic Lsum accumulator
  hipMemsetAsync(lsum, 0, (size_t)BATCH * NH * TSEQ * 4, stream);

  // 1) conversions + bias concat
  {
    int n4 = MROWS * D_MODEL / 4;
    cvt_f32_to_bf16<<<n4 / 256, 256, 0, stream>>>(x, xb, n4);
    int w4 = 4 * D_MODEL * D_MODEL / 4;
    cvt4_weights<<<w4 / 256, 256, 0, stream>>>(Wq, Wk, Wv, Wo, wqb);
    concat_bias<<<12, 256, 0, stream>>>(bq, bk, bv, bcat);
  }

  // 2) fused QKV projection: [8192x1024] @ [3072x1024]^T -> qkv[8192][3072]
  gemm128<true, false, false><<<dim3(QKV_LD / 128, MROWS / 128), 256, 0, stream>>>(
      xb, wqb, bcat, qkv, D_MODEL, QKV_LD, 0, 0, 0);

  // 3) V transpose (V = qkv cols 2048..3071)
  transpose_v<<<dim3(TSEQ / 64, D_MODEL / 64, BATCH), 256, 0, stream>>>(qkv + 2048, vtb);

  // 4) stats: Lsum partials (atomic), then invert
  attn4w<0><<<dim3(TSEQ / 128, TSEQ / 128, BATCH), 256, 0, stream>>>(qkv, nullptr, lsum);
  invert_lsum<<<(BATCH * NH * TSEQ) / 256, 256, 0, stream>>>(lsum, BATCH * NH * TSEQ);

  // 5) head-averaged attention -> alpha
  attn4w<1><<<dim3(TSEQ / 128, TSEQ / 128, BATCH), 256, 0, stream>>>(qkv, lsum, alpha);

  // 6) Mid = alpha @ V
  gemm128<true, true, true><<<dim3(D_MODEL / 128, TSEQ / 128, BATCH), 256, 0, stream>>>(
      alpha, vtb, nullptr, midb, TSEQ, D_MODEL,
      (size_t)TSEQ * TSEQ, (size_t)D_MODEL * TSEQ, (size_t)TSEQ * D_MODEL);

  // 7) out = Mid @ Wo^T + bo
  gemm128<false, false, false><<<dim3(D_MODEL / 128, MROWS / 128), 256, 0, stream>>>(
      midb, wob, bo, out_f, D_MODEL, D_MODEL, 0, 0, 0);
}

// Round 6
// 375.242 us; speedup vs baseline: 1.3613x; 1.3613x over previous
//
#include <hip/hip_runtime.h>
#include <hip/hip_bf16.h>

#define D_MODEL 1024
#define NH 8
#define HD 128
#define BATCH 4
#define TSEQ 2048
#define MROWS (BATCH * TSEQ)  // 8192
#define QKV_LD 3072           // fused q|k|v row stride

typedef __attribute__((ext_vector_type(8))) __bf16 bf16x8;
typedef __attribute__((ext_vector_type(4))) __bf16 bf16x4;
typedef __attribute__((ext_vector_type(4))) float f32x4;
typedef __attribute__((ext_vector_type(8))) unsigned short u16x8;

#define SC2 0.1275174441680632f  // (1/sqrt(128)) * log2(e)

__device__ __forceinline__ void gload16(const void* g, void* lds) {
  __builtin_amdgcn_global_load_lds(
      (const __attribute__((address_space(1))) unsigned int*)g,
      (__attribute__((address_space(3))) unsigned int*)lds, 16, 0, 0);
}

// ---------------- small conversion / setup kernels ----------------
__global__ __launch_bounds__(256) void cvt_f32_to_bf16(const float* __restrict__ in,
                                                       __bf16* __restrict__ out, int n4) {
  int i = blockIdx.x * 256 + threadIdx.x;
  if (i < n4) {
    float4 v = reinterpret_cast<const float4*>(in)[i];
    bf16x4 o;
    o[0] = (__bf16)v.x; o[1] = (__bf16)v.y; o[2] = (__bf16)v.z; o[3] = (__bf16)v.w;
    reinterpret_cast<bf16x4*>(out)[i] = o;
  }
}

__global__ __launch_bounds__(256) void cvt4_weights(const float* __restrict__ w0,
                                                    const float* __restrict__ w1,
                                                    const float* __restrict__ w2,
                                                    const float* __restrict__ w3,
                                                    __bf16* __restrict__ out) {
  const int per = D_MODEL * D_MODEL / 4;
  int i = blockIdx.x * 256 + threadIdx.x;
  int m = i / per, j = i - m * per;
  const float* src = (m == 0) ? w0 : (m == 1) ? w1 : (m == 2) ? w2 : w3;
  float4 v = reinterpret_cast<const float4*>(src)[j];
  bf16x4 o;
  o[0] = (__bf16)v.x; o[1] = (__bf16)v.y; o[2] = (__bf16)v.z; o[3] = (__bf16)v.w;
  reinterpret_cast<bf16x4*>(out)[i] = o;
}

__global__ __launch_bounds__(256) void concat_bias(const float* __restrict__ a,
                                                   const float* __restrict__ b,
                                                   const float* __restrict__ c,
                                                   float* __restrict__ o) {
  int i = blockIdx.x * 256 + threadIdx.x;
  if (i < 3072) o[i] = (i < 1024) ? a[i] : (i < 2048) ? b[i - 1024] : c[i - 2048];
}

__global__ __launch_bounds__(256) void invert_lsum(float* __restrict__ L, int n) {
  int i = blockIdx.x * 256 + threadIdx.x;
  if (i < n) L[i] = 1.0f / (8.0f * L[i]);
}

// ---------------- generic 128x128 GEMM:  Y = A @ B^T (+bias), 2-phase dbuf ----
template <bool BF16OUT, bool CAUSAL, bool AFP32>
__global__ __launch_bounds__(256) void gemm128(const void* __restrict__ Aip,
                                               const __bf16* __restrict__ Bp,
                                               const float* __restrict__ bias,
                                               void* __restrict__ Yp, int K, int ldy,
                                               size_t sA, size_t sB, size_t sY) {
  __shared__ __bf16 As[2][128 * 32];
  __shared__ __bf16 Bs[2][128 * 32];
  const int tid = threadIdx.x;
  const int w = tid >> 6, l = tid & 63;
  const int lr = l & 15, lg = l >> 4;
  const int m0 = blockIdx.y * 128, n0 = blockIdx.x * 128;
  const int z = blockIdx.z;
  const __bf16* Ab = AFP32 ? nullptr : (const __bf16*)Aip + z * sA;
  const float* Af = AFP32 ? (const float*)Aip + z * sA : nullptr;
  const __bf16* Bb = Bp + z * sB;
  const int wm = w >> 1, wn = w & 1;
  f32x4 acc[4][4] = {};
  const int Klim = CAUSAL ? (m0 + 128 < K ? m0 + 128 : K) : K;
  const int nt = Klim >> 5;

  auto stage = [&](int t, int buf) {
    const int k0 = t << 5;
    if constexpr (!AFP32) {
#pragma unroll
      for (int i = 0; i < 2; ++i) {
        int s = w * 128 + i * 64 + l;
        int row = s >> 2, scp = s & 3;
        int sc = scp ^ ((row >> 1) & 3);
        gload16(Ab + (size_t)(m0 + row) * K + k0 + sc * 8, (char*)As[buf] + s * 16);
      }
    } else {
#pragma unroll
      for (int i = 0; i < 2; ++i) {
        int s = w * 128 + i * 64 + l;
        int row = s >> 2, sc = s & 3;
        const float* src = Af + (size_t)(m0 + row) * K + k0 + sc * 8;
        float4 lo = *reinterpret_cast<const float4*>(src);
        float4 hi = *reinterpret_cast<const float4*>(src + 4);
        bf16x8 v;
        v[0] = (__bf16)lo.x; v[1] = (__bf16)lo.y; v[2] = (__bf16)lo.z; v[3] = (__bf16)lo.w;
        v[4] = (__bf16)hi.x; v[5] = (__bf16)hi.y; v[6] = (__bf16)hi.z; v[7] = (__bf16)hi.w;
        int p = row * 4 + (sc ^ ((row >> 1) & 3));
        *reinterpret_cast<bf16x8*>((char*)As[buf] + p * 16) = v;
      }
    }
#pragma unroll
    for (int i = 0; i < 2; ++i) {
      int s = w * 128 + i * 64 + l;
      int row = s >> 2, scp = s & 3;
      int sc = scp ^ ((row >> 1) & 3);
      gload16(Bb + (size_t)(n0 + row) * K + k0 + sc * 8, (char*)Bs[buf] + s * 16);
    }
  };

  stage(0, 0);
  __syncthreads();
  int cur = 0;
  for (int t = 0; t < nt; ++t) {
    if (t + 1 < nt) stage(t + 1, cur ^ 1);
    bf16x8 af[4], bf[4];
#pragma unroll
    for (int f = 0; f < 4; ++f) {
      int ar = wm * 64 + f * 16 + lr;
      af[f] = *reinterpret_cast<const bf16x8*>((const char*)As[cur] + ar * 64 +
                                               ((lg ^ ((ar >> 1) & 3)) * 16));
      int br = wn * 64 + f * 16 + lr;
      bf[f] = *reinterpret_cast<const bf16x8*>((const char*)Bs[cur] + br * 64 +
                                               ((lg ^ ((br >> 1) & 3)) * 16));
    }
#pragma unroll
    for (int mf = 0; mf < 4; ++mf)
#pragma unroll
      for (int nf = 0; nf < 4; ++nf)
        acc[mf][nf] = __builtin_amdgcn_mfma_f32_16x16x32_bf16(af[mf], bf[nf], acc[mf][nf], 0, 0, 0);
    __syncthreads();
    cur ^= 1;
  }

#pragma unroll
  for (int mf = 0; mf < 4; ++mf) {
#pragma unroll
    for (int nf = 0; nf < 4; ++nf) {
#pragma unroll
      for (int r = 0; r < 4; ++r) {
        int grow = m0 + wm * 64 + mf * 16 + lg * 4 + r;
        int gcol = n0 + wn * 64 + nf * 16 + lr;
        float v = acc[mf][nf][r];
        if (bias) v += bias[gcol];
        if constexpr (BF16OUT)
          ((__bf16*)Yp + z * sY)[(size_t)grow * ldy + gcol] = (__bf16)v;
        else
          ((float*)Yp + z * sY)[(size_t)grow * ldy + gcol] = v;
      }
    }
  }
}

// ---------------- V[b][t][d] (ld=QKV_LD) -> Vt[b][d][t] ----------------
__global__ __launch_bounds__(256) void transpose_v(const __bf16* __restrict__ V,
                                                   __bf16* __restrict__ Vt) {
  __shared__ unsigned short tile[64 * 72];
  const int b = blockIdx.z;
  const int t0 = blockIdx.x * 64, d0 = blockIdx.y * 64;
  const int tid = threadIdx.x;
#pragma unroll
  for (int i = 0; i < 2; ++i) {
    int s = i * 256 + tid;
    int r = s >> 3, c8 = s & 7;
    u16x8 v = *reinterpret_cast<const u16x8*>(V + ((size_t)b * TSEQ + t0 + r) * QKV_LD + d0 + c8 * 8);
    *reinterpret_cast<u16x8*>(&tile[r * 72 + c8 * 8]) = v;
  }
  __syncthreads();
#pragma unroll
  for (int i = 0; i < 2; ++i) {
    int s = i * 256 + tid;
    int dr = s >> 3, t8 = s & 7;
    u16x8 o;
#pragma unroll
    for (int j = 0; j < 8; ++j) o[j] = tile[(t8 * 8 + j) * 72 + dr];
    *reinterpret_cast<u16x8*>(Vt + ((size_t)b * D_MODEL + d0 + dr) * TSEQ + t0 + t8 * 8) = o;
  }
}

// ---------------- attention passes, gemm128-shaped ----------------
// 512 thr / 8 waves as 4(wq: 32-row bands) x 2(wk: 64-col halves) of a 128x128
// score tile. K-reduction = qkv cols 0..1023 (8 heads x BK=32 x 4), 2-phase
// dbuf, 32KB LDS. Epilogue every 4 k-steps finishes head h = t>>2 in regs.
// MODE 0: Lsum partials via atomicAdd.  MODE 1: alpha = sum_h exp*Linv.
template <int MODE>
__global__ __launch_bounds__(512, 4) void attn8w(const __bf16* __restrict__ QKV,
                                                 const float* __restrict__ Linv,
                                                 float* __restrict__ Out) {
  const int kt = blockIdx.x, qt = blockIdx.y, b = blockIdx.z;
  const int q0 = qt * 128, k0 = kt * 128;
  const int tid = threadIdx.x;
  if (kt > qt) {
    if (MODE == 1) {
      float4 zz = {0.f, 0.f, 0.f, 0.f};
#pragma unroll
      for (int i = 0; i < 8; ++i) {
        int s = i * 512 + tid;  // 4096 float4s
        int row = s >> 5, c = s & 31;
        *reinterpret_cast<float4*>(Out + ((size_t)(b * TSEQ) + q0 + row) * TSEQ + k0 + c * 4) = zz;
      }
    }
    return;
  }
  __shared__ __bf16 As[2][128 * 32];
  __shared__ __bf16 Bs[2][128 * 32];
  const int w = tid >> 6, l = tid & 63;
  const int lr = l & 15, lg = l >> 4;
  const int wq = w >> 1, wk = w & 1;
  const __bf16* Qb = QKV + (size_t)(b * TSEQ + q0) * QKV_LD;         // Q cols 0..1023
  const __bf16* Kb = QKV + (size_t)(b * TSEQ + k0) * QKV_LD + 1024;  // K cols
  // staging: phys seg = tid (512 segs of 16B = one [128][32] sliver)
  const int srow = tid >> 2, ssl = (tid & 3) ^ ((srow >> 1) & 3);
  const __bf16* qsrc = Qb + (size_t)srow * QKV_LD + ssl * 8;
  const __bf16* ksrc = Kb + (size_t)srow * QKV_LD + ssl * 8;

  gload16(qsrc, (char*)As[0] + tid * 16);
  gload16(ksrc, (char*)Bs[0] + tid * 16);
  __syncthreads();

  f32x4 acc[2][4] = {};
  float outv[2][4][4] = {};
  const bool diag = (kt == qt);
  int cur = 0;
#pragma unroll 1
  for (int t = 0; t < 32; ++t) {
    if (t < 31) {
      gload16(qsrc + (t + 1) * 32, (char*)As[cur ^ 1] + tid * 16);
      gload16(ksrc + (t + 1) * 32, (char*)Bs[cur ^ 1] + tid * 16);
    }
    bf16x8 af[2], bf[4];
#pragma unroll
    for (int f = 0; f < 2; ++f) {
      int ar = wq * 32 + f * 16 + lr;
      af[f] = *reinterpret_cast<const bf16x8*>((const char*)As[cur] + ar * 64 +
                                               ((lg ^ ((ar >> 1) & 3)) * 16));
    }
#pragma unroll
    for (int g = 0; g < 4; ++g) {
      int br = wk * 64 + g * 16 + lr;
      bf[g] = *reinterpret_cast<const bf16x8*>((const char*)Bs[cur] + br * 64 +
                                               ((lg ^ ((br >> 1) & 3)) * 16));
    }
#pragma unroll
    for (int f = 0; f < 2; ++f)
#pragma unroll
      for (int g = 0; g < 4; ++g)
        acc[f][g] = __builtin_amdgcn_mfma_f32_16x16x32_bf16(af[f], bf[g], acc[f][g], 0, 0, 0);

    if ((t & 3) == 3) {  // head h = t>>2 complete; finish in registers
      const int h = t >> 2;
      if constexpr (MODE == 0) {
        float ls[2][4] = {};
#pragma unroll
        for (int f = 0; f < 2; ++f)
#pragma unroll
          for (int g = 0; g < 4; ++g)
#pragma unroll
            for (int r = 0; r < 4; ++r) {
              int q = wq * 32 + f * 16 + lg * 4 + r;
              int k = wk * 64 + g * 16 + lr;
              if (!diag || k <= q) ls[f][r] += exp2f(acc[f][g][r] * SC2);
              acc[f][g][r] = 0.f;
            }
#pragma unroll
        for (int m = 1; m < 16; m <<= 1)
#pragma unroll
          for (int f = 0; f < 2; ++f)
#pragma unroll
            for (int r = 0; r < 4; ++r) ls[f][r] += __shfl_xor(ls[f][r], m, 64);
        if (lr == 0) {
#pragma unroll
          for (int f = 0; f < 2; ++f)
#pragma unroll
            for (int r = 0; r < 4; ++r)
              atomicAdd(&Out[((size_t)(b * NH + h)) * TSEQ + q0 + wq * 32 + f * 16 + lg * 4 + r],
                        ls[f][r]);
        }
      } else {
        float li[2][4];
#pragma unroll
        for (int f = 0; f < 2; ++f) {
          float4 v = *reinterpret_cast<const float4*>(
              &Linv[((size_t)(b * NH + h)) * TSEQ + q0 + wq * 32 + f * 16 + lg * 4]);
          li[f][0] = v.x; li[f][1] = v.y; li[f][2] = v.z; li[f][3] = v.w;
        }
#pragma unroll
        for (int f = 0; f < 2; ++f)
#pragma unroll
          for (int g = 0; g < 4; ++g)
#pragma unroll
            for (int r = 0; r < 4; ++r) {
              int q = wq * 32 + f * 16 + lg * 4 + r;
              int k = wk * 64 + g * 16 + lr;
              if (!diag || k <= q)
                outv[f][g][r] += exp2f(acc[f][g][r] * SC2) * li[f][r];
              acc[f][g][r] = 0.f;
            }
      }
    }
    __syncthreads();
    cur ^= 1;
  }
  if constexpr (MODE == 1) {
#pragma unroll
    for (int f = 0; f < 2; ++f)
#pragma unroll
      for (int g = 0; g < 4; ++g)
#pragma unroll
        for (int r = 0; r < 4; ++r)
          Out[((size_t)(b * TSEQ) + q0 + wq * 32 + f * 16 + lg * 4 + r) * TSEQ +
              k0 + wk * 64 + g * 16 + lr] = outv[f][g][r];
  }
}

extern "C" void kernel_launch(void* const* d_in, const int* in_sizes, int n_in,
                              void* d_out, int out_size, void* d_ws, size_t ws_size,
                              hipStream_t stream) {
  const float* x  = (const float*)d_in[0];
  const float* Wq = (const float*)d_in[2];
  const float* bq = (const float*)d_in[3];
  const float* Wk = (const float*)d_in[4];
  const float* bk = (const float*)d_in[5];
  const float* Wv = (const float*)d_in[6];
  const float* bv = (const float*)d_in[7];
  const float* Wo = (const float*)d_in[8];
  const float* bo = (const float*)d_in[9];

  float* out_f = (float*)d_out;                    // [4,2048,1024]
  float* alpha = out_f + (size_t)MROWS * D_MODEL;  // [4,2048,2048]

  char* p = (char*)d_ws;
  __bf16* xb   = (__bf16*)p; p += (size_t)MROWS * D_MODEL * 2;      // reused as midb
  __bf16* wqb  = (__bf16*)p; p += (size_t)D_MODEL * D_MODEL * 2;    // wq|wk|wv|wo contiguous
  __bf16* wkb  = (__bf16*)p; p += (size_t)D_MODEL * D_MODEL * 2;
  __bf16* wvb  = (__bf16*)p; p += (size_t)D_MODEL * D_MODEL * 2;
  __bf16* wob  = (__bf16*)p; p += (size_t)D_MODEL * D_MODEL * 2;
  __bf16* qkv  = (__bf16*)p; p += (size_t)MROWS * QKV_LD * 2;       // 48 MB
  __bf16* vtb  = (__bf16*)p; p += (size_t)BATCH * D_MODEL * TSEQ * 2;
  float* lsum  = (float*)p;  p += (size_t)BATCH * NH * TSEQ * 4;
  float* bcat  = (float*)p;  p += 3072 * 4;
  __bf16* midb = xb;

  // 0) zero the atomic Lsum accumulator
  hipMemsetAsync(lsum, 0, (size_t)BATCH * NH * TSEQ * 4, stream);

  // 1) conversions + bias concat
  {
    int n4 = MROWS * D_MODEL / 4;
    cvt_f32_to_bf16<<<n4 / 256, 256, 0, stream>>>(x, xb, n4);
    int w4 = 4 * D_MODEL * D_MODEL / 4;
    cvt4_weights<<<w4 / 256, 256, 0, stream>>>(Wq, Wk, Wv, Wo, wqb);
    concat_bias<<<12, 256, 0, stream>>>(bq, bk, bv, bcat);
  }

  // 2) fused QKV projection: [8192x1024] @ [3072x1024]^T -> qkv[8192][3072]
  gemm128<true, false, false><<<dim3(QKV_LD / 128, MROWS / 128), 256, 0, stream>>>(
      xb, wqb, bcat, qkv, D_MODEL, QKV_LD, 0, 0, 0);

  // 3) V transpose (V = qkv cols 2048..3071)
  transpose_v<<<dim3(TSEQ / 64, D_MODEL / 64, BATCH), 256, 0, stream>>>(qkv + 2048, vtb);

  // 4) stats: Lsum partials (atomic), then invert
  attn8w<0><<<dim3(TSEQ / 128, TSEQ / 128, BATCH), 512, 0, stream>>>(qkv, nullptr, lsum);
  invert_lsum<<<(BATCH * NH * TSEQ) / 256, 256, 0, stream>>>(lsum, BATCH * NH * TSEQ);

  // 5) head-averaged attention -> alpha
  attn8w<1><<<dim3(TSEQ / 128, TSEQ / 128, BATCH), 512, 0, stream>>>(qkv, lsum, alpha);

  // 6) Mid = alpha @ V
  gemm128<true, true, true><<<dim3(D_MODEL / 128, TSEQ / 128, BATCH), 256, 0, stream>>>(
      alpha, vtb, nullptr, midb, TSEQ, D_MODEL,
      (size_t)TSEQ * TSEQ, (size_t)D_MODEL * TSEQ, (size_t)TSEQ * D_MODEL);

  // 7) out = Mid @ Wo^T + bo
  gemm128<false, false, false><<<dim3(D_MODEL / 128, MROWS / 128), 256, 0, stream>>>(
      midb, wob, bo, out_f, D_MODEL, D_MODEL, 0, 0, 0);
}

// Round 7
// 368.820 us; speedup vs baseline: 1.3850x; 1.0174x over previous
//
#include <hip/hip_runtime.h>
#include <hip/hip_bf16.h>

#define D_MODEL 1024
#define NH 8
#define HD 128
#define BATCH 4
#define TSEQ 2048
#define MROWS (BATCH * TSEQ)  // 8192
#define QKV_LD 3072           // fused q|k|v row stride
#define SBAND 131072          // 8*128*128 elems per (qt-band unit)

typedef __attribute__((ext_vector_type(8))) __bf16 bf16x8;
typedef __attribute__((ext_vector_type(4))) __bf16 bf16x4;
typedef __attribute__((ext_vector_type(4))) float f32x4;
typedef __attribute__((ext_vector_type(8))) unsigned short u16x8;

#define SC2 0.1275174441680632f  // (1/sqrt(128)) * log2(e)

__device__ __forceinline__ void gload16(const void* g, void* lds) {
  __builtin_amdgcn_global_load_lds(
      (const __attribute__((address_space(1))) unsigned int*)g,
      (__attribute__((address_space(3))) unsigned int*)lds, 16, 0, 0);
}

// ---------------- small conversion / setup kernels ----------------
__global__ __launch_bounds__(256) void cvt_f32_to_bf16(const float* __restrict__ in,
                                                       __bf16* __restrict__ out, int n4) {
  int i = blockIdx.x * 256 + threadIdx.x;
  if (i < n4) {
    float4 v = reinterpret_cast<const float4*>(in)[i];
    bf16x4 o;
    o[0] = (__bf16)v.x; o[1] = (__bf16)v.y; o[2] = (__bf16)v.z; o[3] = (__bf16)v.w;
    reinterpret_cast<bf16x4*>(out)[i] = o;
  }
}

__global__ __launch_bounds__(256) void cvt4_weights(const float* __restrict__ w0,
                                                    const float* __restrict__ w1,
                                                    const float* __restrict__ w2,
                                                    const float* __restrict__ w3,
                                                    __bf16* __restrict__ out) {
  const int per = D_MODEL * D_MODEL / 4;
  int i = blockIdx.x * 256 + threadIdx.x;
  int m = i / per, j = i - m * per;
  const float* src = (m == 0) ? w0 : (m == 1) ? w1 : (m == 2) ? w2 : w3;
  float4 v = reinterpret_cast<const float4*>(src)[j];
  bf16x4 o;
  o[0] = (__bf16)v.x; o[1] = (__bf16)v.y; o[2] = (__bf16)v.z; o[3] = (__bf16)v.w;
  reinterpret_cast<bf16x4*>(out)[i] = o;
}

__global__ __launch_bounds__(256) void concat_bias(const float* __restrict__ a,
                                                   const float* __restrict__ b,
                                                   const float* __restrict__ c,
                                                   float* __restrict__ o) {
  int i = blockIdx.x * 256 + threadIdx.x;
  if (i < 3072) o[i] = (i < 1024) ? a[i] : (i < 2048) ? b[i - 1024] : c[i - 2048];
}

__global__ __launch_bounds__(256) void invert_lsum(float* __restrict__ L, int n) {
  int i = blockIdx.x * 256 + threadIdx.x;
  if (i < n) L[i] = 1.0f / (8.0f * L[i]);
}

// ---------------- generic 128x128 GEMM:  Y = A @ B^T (+bias), 2-phase dbuf ----
template <bool BF16OUT, bool CAUSAL, bool AFP32>
__global__ __launch_bounds__(256) void gemm128(const void* __restrict__ Aip,
                                               const __bf16* __restrict__ Bp,
                                               const float* __restrict__ bias,
                                               void* __restrict__ Yp, int K, int ldy,
                                               size_t sA, size_t sB, size_t sY) {
  __shared__ __bf16 As[2][128 * 32];
  __shared__ __bf16 Bs[2][128 * 32];
  const int tid = threadIdx.x;
  const int w = tid >> 6, l = tid & 63;
  const int lr = l & 15, lg = l >> 4;
  const int m0 = blockIdx.y * 128, n0 = blockIdx.x * 128;
  const int z = blockIdx.z;
  const __bf16* Ab = AFP32 ? nullptr : (const __bf16*)Aip + z * sA;
  const float* Af = AFP32 ? (const float*)Aip + z * sA : nullptr;
  const __bf16* Bb = Bp + z * sB;
  const int wm = w >> 1, wn = w & 1;
  f32x4 acc[4][4] = {};
  const int Klim = CAUSAL ? (m0 + 128 < K ? m0 + 128 : K) : K;
  const int nt = Klim >> 5;

  auto stage = [&](int t, int buf) {
    const int k0 = t << 5;
    if constexpr (!AFP32) {
#pragma unroll
      for (int i = 0; i < 2; ++i) {
        int s = w * 128 + i * 64 + l;
        int row = s >> 2, scp = s & 3;
        int sc = scp ^ ((row >> 1) & 3);
        gload16(Ab + (size_t)(m0 + row) * K + k0 + sc * 8, (char*)As[buf] + s * 16);
      }
    } else {
#pragma unroll
      for (int i = 0; i < 2; ++i) {
        int s = w * 128 + i * 64 + l;
        int row = s >> 2, sc = s & 3;
        const float* src = Af + (size_t)(m0 + row) * K + k0 + sc * 8;
        float4 lo = *reinterpret_cast<const float4*>(src);
        float4 hi = *reinterpret_cast<const float4*>(src + 4);
        bf16x8 v;
        v[0] = (__bf16)lo.x; v[1] = (__bf16)lo.y; v[2] = (__bf16)lo.z; v[3] = (__bf16)lo.w;
        v[4] = (__bf16)hi.x; v[5] = (__bf16)hi.y; v[6] = (__bf16)hi.z; v[7] = (__bf16)hi.w;
        int p = row * 4 + (sc ^ ((row >> 1) & 3));
        *reinterpret_cast<bf16x8*>((char*)As[buf] + p * 16) = v;
      }
    }
#pragma unroll
    for (int i = 0; i < 2; ++i) {
      int s = w * 128 + i * 64 + l;
      int row = s >> 2, scp = s & 3;
      int sc = scp ^ ((row >> 1) & 3);
      gload16(Bb + (size_t)(n0 + row) * K + k0 + sc * 8, (char*)Bs[buf] + s * 16);
    }
  };

  stage(0, 0);
  __syncthreads();
  int cur = 0;
  for (int t = 0; t < nt; ++t) {
    if (t + 1 < nt) stage(t + 1, cur ^ 1);
    bf16x8 af[4], bf[4];
#pragma unroll
    for (int f = 0; f < 4; ++f) {
      int ar = wm * 64 + f * 16 + lr;
      af[f] = *reinterpret_cast<const bf16x8*>((const char*)As[cur] + ar * 64 +
                                               ((lg ^ ((ar >> 1) & 3)) * 16));
      int br = wn * 64 + f * 16 + lr;
      bf[f] = *reinterpret_cast<const bf16x8*>((const char*)Bs[cur] + br * 64 +
                                               ((lg ^ ((br >> 1) & 3)) * 16));
    }
#pragma unroll
    for (int mf = 0; mf < 4; ++mf)
#pragma unroll
      for (int nf = 0; nf < 4; ++nf)
        acc[mf][nf] = __builtin_amdgcn_mfma_f32_16x16x32_bf16(af[mf], bf[nf], acc[mf][nf], 0, 0, 0);
    __syncthreads();
    cur ^= 1;
  }

#pragma unroll
  for (int mf = 0; mf < 4; ++mf) {
#pragma unroll
    for (int nf = 0; nf < 4; ++nf) {
#pragma unroll
      for (int r = 0; r < 4; ++r) {
        int grow = m0 + wm * 64 + mf * 16 + lg * 4 + r;
        int gcol = n0 + wn * 64 + nf * 16 + lr;
        float v = acc[mf][nf][r];
        if (bias) v += bias[gcol];
        if constexpr (BF16OUT)
          ((__bf16*)Yp + z * sY)[(size_t)grow * ldy + gcol] = (__bf16)v;
        else
          ((float*)Yp + z * sY)[(size_t)grow * ldy + gcol] = v;
      }
    }
  }
}

// ---------------- V[b][t][d] (ld=QKV_LD) -> Vt[b][d][t] ----------------
__global__ __launch_bounds__(256) void transpose_v(const __bf16* __restrict__ V,
                                                   __bf16* __restrict__ Vt) {
  __shared__ unsigned short tile[64 * 72];
  const int b = blockIdx.z;
  const int t0 = blockIdx.x * 64, d0 = blockIdx.y * 64;
  const int tid = threadIdx.x;
#pragma unroll
  for (int i = 0; i < 2; ++i) {
    int s = i * 256 + tid;
    int r = s >> 3, c8 = s & 7;
    u16x8 v = *reinterpret_cast<const u16x8*>(V + ((size_t)b * TSEQ + t0 + r) * QKV_LD + d0 + c8 * 8);
    *reinterpret_cast<u16x8*>(&tile[r * 72 + c8 * 8]) = v;
  }
  __syncthreads();
#pragma unroll
  for (int i = 0; i < 2; ++i) {
    int s = i * 256 + tid;
    int dr = s >> 3, t8 = s & 7;
    u16x8 o;
#pragma unroll
    for (int j = 0; j < 8; ++j) o[j] = tile[(t8 * 8 + j) * 72 + dr];
    *reinterpret_cast<u16x8*>(Vt + ((size_t)b * D_MODEL + d0 + dr) * TSEQ + t0 + t8 * 8) = o;
  }
}

// ---------------- score GEMM: S tiles (bf16, causal-packed) + Lsum atomics ---
// One batch per launch. Grid (136 causal tiles, 8 heads). Block: 256 thr,
// 128x128 tile, K=128 (4 BK=32 steps, dbuf). Band layout: for q-band qt,
// S[boff(qt) + h*128*kext + row*kext + k], kext=(qt+1)*128.
__global__ __launch_bounds__(256) void score_gemm(const __bf16* __restrict__ QKV,
                                                  __bf16* __restrict__ S,
                                                  float* __restrict__ lsum, int b) {
  __shared__ __bf16 As[2][128 * 32];
  __shared__ __bf16 Bs[2][128 * 32];
  const int tid = threadIdx.x;
  const int w = tid >> 6, l = tid & 63;
  const int lr = l & 15, lg = l >> 4;
  const int wm = w >> 1, wn = w & 1;
  const int idx = blockIdx.x;
  const int h = blockIdx.y;
  int qt = (int)((sqrtf(8.f * (float)idx + 1.f) - 1.f) * 0.5f);
  while ((qt + 1) * (qt + 2) / 2 <= idx) ++qt;
  while (qt * (qt + 1) / 2 > idx) --qt;
  const int kt = idx - qt * (qt + 1) / 2;
  const int q0 = qt * 128, k0 = kt * 128;
  const int kext = (qt + 1) * 128;
  const bool diag = (kt == qt);

  const __bf16* Ab = QKV + (size_t)(b * TSEQ + q0) * QKV_LD + h * HD;         // Q
  const __bf16* Bb = QKV + (size_t)(b * TSEQ + k0) * QKV_LD + 1024 + h * HD;  // K

  auto stage = [&](int t, int buf) {
#pragma unroll
    for (int i = 0; i < 2; ++i) {
      int s = w * 128 + i * 64 + l;
      int row = s >> 2, scp = s & 3;
      int sc = scp ^ ((row >> 1) & 3);
      gload16(Ab + (size_t)row * QKV_LD + t * 32 + sc * 8, (char*)As[buf] + s * 16);
    }
#pragma unroll
    for (int i = 0; i < 2; ++i) {
      int s = w * 128 + i * 64 + l;
      int row = s >> 2, scp = s & 3;
      int sc = scp ^ ((row >> 1) & 3);
      gload16(Bb + (size_t)row * QKV_LD + t * 32 + sc * 8, (char*)Bs[buf] + s * 16);
    }
  };

  f32x4 acc[4][4] = {};
  stage(0, 0);
  __syncthreads();
  int cur = 0;
#pragma unroll
  for (int t = 0; t < 4; ++t) {
    if (t < 3) stage(t + 1, cur ^ 1);
    bf16x8 af[4], bf[4];
#pragma unroll
    for (int f = 0; f < 4; ++f) {
      int ar = wm * 64 + f * 16 + lr;
      af[f] = *reinterpret_cast<const bf16x8*>((const char*)As[cur] + ar * 64 +
                                               ((lg ^ ((ar >> 1) & 3)) * 16));
      int br = wn * 64 + f * 16 + lr;
      bf[f] = *reinterpret_cast<const bf16x8*>((const char*)Bs[cur] + br * 64 +
                                               ((lg ^ ((br >> 1) & 3)) * 16));
    }
#pragma unroll
    for (int mf = 0; mf < 4; ++mf)
#pragma unroll
      for (int nf = 0; nf < 4; ++nf)
        acc[mf][nf] = __builtin_amdgcn_mfma_f32_16x16x32_bf16(af[mf], bf[nf], acc[mf][nf], 0, 0, 0);
    __syncthreads();
    cur ^= 1;
  }

  // epilogue: store bf16 tile + causal-masked exp row-sum atomics
  __bf16* Sb = S + (size_t)SBAND * ((qt * (qt + 1)) >> 1) + (size_t)h * 128 * kext + k0;
  float ls[4][4] = {};
#pragma unroll
  for (int mf = 0; mf < 4; ++mf) {
#pragma unroll
    for (int r = 0; r < 4; ++r) {
      int row = wm * 64 + mf * 16 + lg * 4 + r;
      __bf16* srow = Sb + (size_t)row * kext;
#pragma unroll
      for (int nf = 0; nf < 4; ++nf) {
        int col = wn * 64 + nf * 16 + lr;
        float v = acc[mf][nf][r];
        srow[col] = (__bf16)v;
        if (!diag || col <= row) ls[mf][r] += exp2f(v * SC2);
      }
    }
  }
#pragma unroll
  for (int m = 1; m < 16; m <<= 1)
#pragma unroll
    for (int mf = 0; mf < 4; ++mf)
#pragma unroll
      for (int r = 0; r < 4; ++r) ls[mf][r] += __shfl_xor(ls[mf][r], m, 64);
  if (lr == 0) {
#pragma unroll
    for (int mf = 0; mf < 4; ++mf)
#pragma unroll
      for (int r = 0; r < 4; ++r)
        atomicAdd(&lsum[((size_t)(b * NH + h)) * TSEQ + q0 + wm * 64 + mf * 16 + lg * 4 + r],
                  ls[mf][r]);
  }
}

// ---------------- alpha streaming: alpha[q][k] = sum_h exp(s_h)*Linv ----------
// One batch per launch; one block per q row (256 thr x 8 k each).
__global__ __launch_bounds__(256) void alpha_stream(const __bf16* __restrict__ S,
                                                    const float* __restrict__ Linv,
                                                    float* __restrict__ alpha, int b) {
  const int q = blockIdx.x;
  const int qt = q >> 7;
  const int kext = (qt + 1) * 128;
  const int k0 = threadIdx.x * 8;
  float* arow = alpha + ((size_t)(b * TSEQ + q)) * TSEQ + k0;
  if (k0 >= kext) {
    float4 zz = {0.f, 0.f, 0.f, 0.f};
    *reinterpret_cast<float4*>(arow) = zz;
    *reinterpret_cast<float4*>(arow + 4) = zz;
    return;
  }
  const __bf16* Sb = S + (size_t)SBAND * ((qt * (qt + 1)) >> 1) + (size_t)(q & 127) * kext + k0;
  const size_t hstride = (size_t)128 * kext;
  float o[8] = {};
#pragma unroll
  for (int h = 0; h < NH; ++h) {
    float li = Linv[((size_t)(b * NH + h)) * TSEQ + q];
    bf16x8 s8 = *reinterpret_cast<const bf16x8*>(Sb + h * hstride);
#pragma unroll
    for (int j = 0; j < 8; ++j) o[j] += exp2f((float)s8[j] * SC2) * li;
  }
#pragma unroll
  for (int j = 0; j < 8; ++j)
    if (k0 + j > q) o[j] = 0.f;
  float4 lo = {o[0], o[1], o[2], o[3]};
  float4 hi = {o[4], o[5], o[6], o[7]};
  *reinterpret_cast<float4*>(arow) = lo;
  *reinterpret_cast<float4*>(arow + 4) = hi;
}

extern "C" void kernel_launch(void* const* d_in, const int* in_sizes, int n_in,
                              void* d_out, int out_size, void* d_ws, size_t ws_size,
                              hipStream_t stream) {
  const float* x  = (const float*)d_in[0];
  const float* Wq = (const float*)d_in[2];
  const float* bq = (const float*)d_in[3];
  const float* Wk = (const float*)d_in[4];
  const float* bk = (const float*)d_in[5];
  const float* Wv = (const float*)d_in[6];
  const float* bv = (const float*)d_in[7];
  const float* Wo = (const float*)d_in[8];
  const float* bo = (const float*)d_in[9];

  float* out_f = (float*)d_out;                    // [4,2048,1024]
  float* alpha = out_f + (size_t)MROWS * D_MODEL;  // [4,2048,2048]

  char* p = (char*)d_ws;
  __bf16* xb   = (__bf16*)p; p += (size_t)MROWS * D_MODEL * 2;      // reused as midb
  __bf16* wqb  = (__bf16*)p; p += (size_t)D_MODEL * D_MODEL * 2;    // wq|wk|wv|wo contiguous
  __bf16* wkb  = (__bf16*)p; p += (size_t)D_MODEL * D_MODEL * 2;
  __bf16* wvb  = (__bf16*)p; p += (size_t)D_MODEL * D_MODEL * 2;
  __bf16* wob  = (__bf16*)p; p += (size_t)D_MODEL * D_MODEL * 2;
  __bf16* qkv  = (__bf16*)p; p += (size_t)MROWS * QKV_LD * 2;       // 48 MB
  __bf16* vtb  = (__bf16*)p; p += (size_t)BATCH * D_MODEL * TSEQ * 2;
  float* lsum  = (float*)p;  p += (size_t)BATCH * NH * TSEQ * 4;
  __bf16* sbuf = (__bf16*)p; p += (size_t)SBAND * 136 * 2;          // 35.7 MB, per-batch
  float* bcat  = (float*)p;  p += 3072 * 4;
  __bf16* midb = xb;

  // 0) zero the atomic Lsum accumulator
  hipMemsetAsync(lsum, 0, (size_t)BATCH * NH * TSEQ * 4, stream);

  // 1) conversions + bias concat
  {
    int n4 = MROWS * D_MODEL / 4;
    cvt_f32_to_bf16<<<n4 / 256, 256, 0, stream>>>(x, xb, n4);
    int w4 = 4 * D_MODEL * D_MODEL / 4;
    cvt4_weights<<<w4 / 256, 256, 0, stream>>>(Wq, Wk, Wv, Wo, wqb);
    concat_bias<<<12, 256, 0, stream>>>(bq, bk, bv, bcat);
  }

  // 2) fused QKV projection: [8192x1024] @ [3072x1024]^T -> qkv[8192][3072]
  gemm128<true, false, false><<<dim3(QKV_LD / 128, MROWS / 128), 256, 0, stream>>>(
      xb, wqb, bcat, qkv, D_MODEL, QKV_LD, 0, 0, 0);

  // 3) V transpose (V = qkv cols 2048..3071)
  transpose_v<<<dim3(TSEQ / 64, D_MODEL / 64, BATCH), 256, 0, stream>>>(qkv + 2048, vtb);

  // 4) per batch: scores(+lsum) -> invert -> alpha
  for (int b = 0; b < BATCH; ++b) {
    score_gemm<<<dim3(136, NH), 256, 0, stream>>>(qkv, sbuf, lsum, b);
    invert_lsum<<<(NH * TSEQ) / 256, 256, 0, stream>>>(lsum + (size_t)b * NH * TSEQ, NH * TSEQ);
    alpha_stream<<<TSEQ, 256, 0, stream>>>(sbuf, lsum, alpha, b);
  }

  // 5) Mid = alpha @ V
  gemm128<true, true, true><<<dim3(D_MODEL / 128, TSEQ / 128, BATCH), 256, 0, stream>>>(
      alpha, vtb, nullptr, midb, TSEQ, D_MODEL,
      (size_t)TSEQ * TSEQ, (size_t)D_MODEL * TSEQ, (size_t)TSEQ * D_MODEL);

  // 6) out = Mid @ Wo^T + bo
  gemm128<false, false, false><<<dim3(D_MODEL / 128, MROWS / 128), 256, 0, stream>>>(
      midb, wob, bo, out_f, D_MODEL, D_MODEL, 0, 0, 0);
}

// Round 8
// 363.323 us; speedup vs baseline: 1.4059x; 1.0151x over previous
//
#include <hip/hip_runtime.h>
#include <hip/hip_bf16.h>

#define D_MODEL 1024
#define NH 8
#define HD 128
#define BATCH 4
#define TSEQ 2048
#define MROWS (BATCH * TSEQ)  // 8192
#define QKV_LD 3072           // fused q|k|v row stride
#define SBAND 131072          // 8*128*128 elems per (qt-band unit)
#define SBATCH ((size_t)SBAND * 136)  // score elems per batch

typedef __attribute__((ext_vector_type(8))) __bf16 bf16x8;
typedef __attribute__((ext_vector_type(4))) __bf16 bf16x4;
typedef __attribute__((ext_vector_type(4))) float f32x4;
typedef __attribute__((ext_vector_type(8))) unsigned short u16x8;

#define SC2 0.1275174441680632f  // (1/sqrt(128)) * log2(e)

__device__ __forceinline__ void gload16(const void* g, void* lds) {
  __builtin_amdgcn_global_load_lds(
      (const __attribute__((address_space(1))) unsigned int*)g,
      (__attribute__((address_space(3))) unsigned int*)lds, 16, 0, 0);
}

// m204 bijective XCD swizzle of the linearized grid; returns remapped (x,y,z).
__device__ __forceinline__ dim3 swz_grid() {
  const int nx = gridDim.x, ny = gridDim.y;
  const int nwg = nx * ny * gridDim.z;
  int L = blockIdx.x + nx * (blockIdx.y + ny * blockIdx.z);
  const int q = nwg >> 3, r = nwg & 7;
  const int xcd = L & 7, idx = L >> 3;
  int t = (xcd < r ? xcd * (q + 1) : r * (q + 1) + (xcd - r) * q) + idx;
  dim3 o;
  o.x = t % nx; t /= nx;
  o.y = t % ny;
  o.z = t / ny;
  return o;
}

// ---------------- small conversion / setup kernels ----------------
__global__ __launch_bounds__(256) void cvt_f32_to_bf16(const float* __restrict__ in,
                                                       __bf16* __restrict__ out, int n4) {
  int i = blockIdx.x * 256 + threadIdx.x;
  if (i < n4) {
    float4 v = reinterpret_cast<const float4*>(in)[i];
    bf16x4 o;
    o[0] = (__bf16)v.x; o[1] = (__bf16)v.y; o[2] = (__bf16)v.z; o[3] = (__bf16)v.w;
    reinterpret_cast<bf16x4*>(out)[i] = o;
  }
}

__global__ __launch_bounds__(256) void cvt4_weights(const float* __restrict__ w0,
                                                    const float* __restrict__ w1,
                                                    const float* __restrict__ w2,
                                                    const float* __restrict__ w3,
                                                    __bf16* __restrict__ out) {
  const int per = D_MODEL * D_MODEL / 4;
  int i = blockIdx.x * 256 + threadIdx.x;
  int m = i / per, j = i - m * per;
  const float* src = (m == 0) ? w0 : (m == 1) ? w1 : (m == 2) ? w2 : w3;
  float4 v = reinterpret_cast<const float4*>(src)[j];
  bf16x4 o;
  o[0] = (__bf16)v.x; o[1] = (__bf16)v.y; o[2] = (__bf16)v.z; o[3] = (__bf16)v.w;
  reinterpret_cast<bf16x4*>(out)[i] = o;
}

__global__ __launch_bounds__(256) void concat_bias(const float* __restrict__ a,
                                                   const float* __restrict__ b,
                                                   const float* __restrict__ c,
                                                   float* __restrict__ o) {
  int i = blockIdx.x * 256 + threadIdx.x;
  if (i < 3072) o[i] = (i < 1024) ? a[i] : (i < 2048) ? b[i - 1024] : c[i - 2048];
}

// ---------------- generic 128x128 GEMM:  Y = A @ B^T (+bias), 2-phase dbuf ----
template <bool BF16OUT, bool CAUSAL, bool AFP32>
__global__ __launch_bounds__(256) void gemm128(const void* __restrict__ Aip,
                                               const __bf16* __restrict__ Bp,
                                               const float* __restrict__ bias,
                                               void* __restrict__ Yp, int K, int ldy,
                                               size_t sA, size_t sB, size_t sY) {
  __shared__ __bf16 As[2][128 * 32];
  __shared__ __bf16 Bs[2][128 * 32];
  const dim3 bi = swz_grid();
  const int tid = threadIdx.x;
  const int w = tid >> 6, l = tid & 63;
  const int lr = l & 15, lg = l >> 4;
  const int m0 = bi.y * 128, n0 = bi.x * 128;
  const int z = bi.z;
  const __bf16* Ab = AFP32 ? nullptr : (const __bf16*)Aip + z * sA;
  const float* Af = AFP32 ? (const float*)Aip + z * sA : nullptr;
  const __bf16* Bb = Bp + z * sB;
  const int wm = w >> 1, wn = w & 1;
  f32x4 acc[4][4] = {};
  const int Klim = CAUSAL ? (m0 + 128 < K ? m0 + 128 : K) : K;
  const int nt = Klim >> 5;

  auto stage = [&](int t, int buf) {
    const int k0 = t << 5;
    if constexpr (!AFP32) {
#pragma unroll
      for (int i = 0; i < 2; ++i) {
        int s = w * 128 + i * 64 + l;
        int row = s >> 2, scp = s & 3;
        int sc = scp ^ ((row >> 1) & 3);
        gload16(Ab + (size_t)(m0 + row) * K + k0 + sc * 8, (char*)As[buf] + s * 16);
      }
    } else {
#pragma unroll
      for (int i = 0; i < 2; ++i) {
        int s = w * 128 + i * 64 + l;
        int row = s >> 2, sc = s & 3;
        const float* src = Af + (size_t)(m0 + row) * K + k0 + sc * 8;
        float4 lo = *reinterpret_cast<const float4*>(src);
        float4 hi = *reinterpret_cast<const float4*>(src + 4);
        bf16x8 v;
        v[0] = (__bf16)lo.x; v[1] = (__bf16)lo.y; v[2] = (__bf16)lo.z; v[3] = (__bf16)lo.w;
        v[4] = (__bf16)hi.x; v[5] = (__bf16)hi.y; v[6] = (__bf16)hi.z; v[7] = (__bf16)hi.w;
        int p = row * 4 + (sc ^ ((row >> 1) & 3));
        *reinterpret_cast<bf16x8*>((char*)As[buf] + p * 16) = v;
      }
    }
#pragma unroll
    for (int i = 0; i < 2; ++i) {
      int s = w * 128 + i * 64 + l;
      int row = s >> 2, scp = s & 3;
      int sc = scp ^ ((row >> 1) & 3);
      gload16(Bb + (size_t)(n0 + row) * K + k0 + sc * 8, (char*)Bs[buf] + s * 16);
    }
  };

  stage(0, 0);
  __syncthreads();
  int cur = 0;
  for (int t = 0; t < nt; ++t) {
    if (t + 1 < nt) stage(t + 1, cur ^ 1);
    bf16x8 af[4], bf[4];
#pragma unroll
    for (int f = 0; f < 4; ++f) {
      int ar = wm * 64 + f * 16 + lr;
      af[f] = *reinterpret_cast<const bf16x8*>((const char*)As[cur] + ar * 64 +
                                               ((lg ^ ((ar >> 1) & 3)) * 16));
      int br = wn * 64 + f * 16 + lr;
      bf[f] = *reinterpret_cast<const bf16x8*>((const char*)Bs[cur] + br * 64 +
                                               ((lg ^ ((br >> 1) & 3)) * 16));
    }
#pragma unroll
    for (int mf = 0; mf < 4; ++mf)
#pragma unroll
      for (int nf = 0; nf < 4; ++nf)
        acc[mf][nf] = __builtin_amdgcn_mfma_f32_16x16x32_bf16(af[mf], bf[nf], acc[mf][nf], 0, 0, 0);
    __syncthreads();
    cur ^= 1;
  }

#pragma unroll
  for (int mf = 0; mf < 4; ++mf) {
#pragma unroll
    for (int nf = 0; nf < 4; ++nf) {
#pragma unroll
      for (int r = 0; r < 4; ++r) {
        int grow = m0 + wm * 64 + mf * 16 + lg * 4 + r;
        int gcol = n0 + wn * 64 + nf * 16 + lr;
        float v = acc[mf][nf][r];
        if (bias) v += bias[gcol];
        if constexpr (BF16OUT)
          ((__bf16*)Yp + z * sY)[(size_t)grow * ldy + gcol] = (__bf16)v;
        else
          ((float*)Yp + z * sY)[(size_t)grow * ldy + gcol] = v;
      }
    }
  }
}

// ---------------- V[b][t][d] (ld=QKV_LD) -> Vt[b][d][t] ----------------
__global__ __launch_bounds__(256) void transpose_v(const __bf16* __restrict__ V,
                                                   __bf16* __restrict__ Vt) {
  __shared__ unsigned short tile[64 * 72];
  const int b = blockIdx.z;
  const int t0 = blockIdx.x * 64, d0 = blockIdx.y * 64;
  const int tid = threadIdx.x;
#pragma unroll
  for (int i = 0; i < 2; ++i) {
    int s = i * 256 + tid;
    int r = s >> 3, c8 = s & 7;
    u16x8 v = *reinterpret_cast<const u16x8*>(V + ((size_t)b * TSEQ + t0 + r) * QKV_LD + d0 + c8 * 8);
    *reinterpret_cast<u16x8*>(&tile[r * 72 + c8 * 8]) = v;
  }
  __syncthreads();
#pragma unroll
  for (int i = 0; i < 2; ++i) {
    int s = i * 256 + tid;
    int dr = s >> 3, t8 = s & 7;
    u16x8 o;
#pragma unroll
    for (int j = 0; j < 8; ++j) o[j] = tile[(t8 * 8 + j) * 72 + dr];
    *reinterpret_cast<u16x8*>(Vt + ((size_t)b * D_MODEL + d0 + dr) * TSEQ + t0 + t8 * 8) = o;
  }
}

// ---------------- score GEMM: S tiles (bf16, causal-packed) + Lsum atomics ---
// Grid (136 causal tiles, 8 heads, NB batches). Block: 256 thr, 128x128 tile,
// K=128 (4 BK=32 steps, dbuf). Band layout: for q-band qt,
// S[zz*sstride + boff(qt) + h*128*kext + row*kext + k], kext=(qt+1)*128.
__global__ __launch_bounds__(256) void score_gemm(const __bf16* __restrict__ QKV,
                                                  __bf16* __restrict__ S,
                                                  float* __restrict__ lsum,
                                                  int b0, size_t sstride) {
  __shared__ __bf16 As[2][128 * 32];
  __shared__ __bf16 Bs[2][128 * 32];
  const dim3 bi = swz_grid();
  const int tid = threadIdx.x;
  const int w = tid >> 6, l = tid & 63;
  const int lr = l & 15, lg = l >> 4;
  const int wm = w >> 1, wn = w & 1;
  const int idx = bi.x;
  const int h = bi.y;
  const int zz = bi.z;
  const int b = b0 + zz;
  int qt = (int)((sqrtf(8.f * (float)idx + 1.f) - 1.f) * 0.5f);
  while ((qt + 1) * (qt + 2) / 2 <= idx) ++qt;
  while (qt * (qt + 1) / 2 > idx) --qt;
  const int kt = idx - qt * (qt + 1) / 2;
  const int q0 = qt * 128, k0 = kt * 128;
  const int kext = (qt + 1) * 128;
  const bool diag = (kt == qt);

  const __bf16* Ab = QKV + (size_t)(b * TSEQ + q0) * QKV_LD + h * HD;         // Q
  const __bf16* Bb = QKV + (size_t)(b * TSEQ + k0) * QKV_LD + 1024 + h * HD;  // K

  auto stage = [&](int t, int buf) {
#pragma unroll
    for (int i = 0; i < 2; ++i) {
      int s = w * 128 + i * 64 + l;
      int row = s >> 2, scp = s & 3;
      int sc = scp ^ ((row >> 1) & 3);
      gload16(Ab + (size_t)row * QKV_LD + t * 32 + sc * 8, (char*)As[buf] + s * 16);
    }
#pragma unroll
    for (int i = 0; i < 2; ++i) {
      int s = w * 128 + i * 64 + l;
      int row = s >> 2, scp = s & 3;
      int sc = scp ^ ((row >> 1) & 3);
      gload16(Bb + (size_t)row * QKV_LD + t * 32 + sc * 8, (char*)Bs[buf] + s * 16);
    }
  };

  f32x4 acc[4][4] = {};
  stage(0, 0);
  __syncthreads();
  int cur = 0;
#pragma unroll
  for (int t = 0; t < 4; ++t) {
    if (t < 3) stage(t + 1, cur ^ 1);
    bf16x8 af[4], bf[4];
#pragma unroll
    for (int f = 0; f < 4; ++f) {
      int ar = wm * 64 + f * 16 + lr;
      af[f] = *reinterpret_cast<const bf16x8*>((const char*)As[cur] + ar * 64 +
                                               ((lg ^ ((ar >> 1) & 3)) * 16));
      int br = wn * 64 + f * 16 + lr;
      bf[f] = *reinterpret_cast<const bf16x8*>((const char*)Bs[cur] + br * 64 +
                                               ((lg ^ ((br >> 1) & 3)) * 16));
    }
#pragma unroll
    for (int mf = 0; mf < 4; ++mf)
#pragma unroll
      for (int nf = 0; nf < 4; ++nf)
        acc[mf][nf] = __builtin_amdgcn_mfma_f32_16x16x32_bf16(af[mf], bf[nf], acc[mf][nf], 0, 0, 0);
    __syncthreads();
    cur ^= 1;
  }

  // epilogue: store bf16 tile + causal-masked exp row-sum atomics
  __bf16* Sb = S + zz * sstride + (size_t)SBAND * ((qt * (qt + 1)) >> 1) +
               (size_t)h * 128 * kext + k0;
  float ls[4][4] = {};
#pragma unroll
  for (int mf = 0; mf < 4; ++mf) {
#pragma unroll
    for (int r = 0; r < 4; ++r) {
      int row = wm * 64 + mf * 16 + lg * 4 + r;
      __bf16* srow = Sb + (size_t)row * kext;
#pragma unroll
      for (int nf = 0; nf < 4; ++nf) {
        int col = wn * 64 + nf * 16 + lr;
        float v = acc[mf][nf][r];
        srow[col] = (__bf16)v;
        if (!diag || col <= row) ls[mf][r] += exp2f(v * SC2);
      }
    }
  }
#pragma unroll
  for (int m = 1; m < 16; m <<= 1)
#pragma unroll
    for (int mf = 0; mf < 4; ++mf)
#pragma unroll
      for (int r = 0; r < 4; ++r) ls[mf][r] += __shfl_xor(ls[mf][r], m, 64);
  if (lr == 0) {
#pragma unroll
    for (int mf = 0; mf < 4; ++mf)
#pragma unroll
      for (int r = 0; r < 4; ++r)
        atomicAdd(&lsum[((size_t)(b * NH + h)) * TSEQ + q0 + wm * 64 + mf * 16 + lg * 4 + r],
                  ls[mf][r]);
  }
}

// ---------------- alpha streaming: alpha[q][k] = sum_h exp(s_h)/(8*Lsum_h) ----
// Grid (TSEQ, NB). One block per q row (256 thr x 8 k each). Inverts lsum inline.
__global__ __launch_bounds__(256) void alpha_stream(const __bf16* __restrict__ S,
                                                    const float* __restrict__ lsum,
                                                    float* __restrict__ alpha,
                                                    int b0, size_t sstride) {
  const int q = blockIdx.x;
  const int zz = blockIdx.y;
  const int b = b0 + zz;
  const int qt = q >> 7;
  const int kext = (qt + 1) * 128;
  const int k0 = threadIdx.x * 8;
  float* arow = alpha + ((size_t)(b * TSEQ + q)) * TSEQ + k0;
  if (k0 >= kext) {
    float4 zzf = {0.f, 0.f, 0.f, 0.f};
    *reinterpret_cast<float4*>(arow) = zzf;
    *reinterpret_cast<float4*>(arow + 4) = zzf;
    return;
  }
  const __bf16* Sb = S + zz * sstride + (size_t)SBAND * ((qt * (qt + 1)) >> 1) +
                     (size_t)(q & 127) * kext + k0;
  const size_t hstride = (size_t)128 * kext;
  float o[8] = {};
#pragma unroll
  for (int h = 0; h < NH; ++h) {
    float li = 1.0f / (8.0f * lsum[((size_t)(b * NH + h)) * TSEQ + q]);
    bf16x8 s8 = *reinterpret_cast<const bf16x8*>(Sb + h * hstride);
#pragma unroll
    for (int j = 0; j < 8; ++j) o[j] += exp2f((float)s8[j] * SC2) * li;
  }
#pragma unroll
  for (int j = 0; j < 8; ++j)
    if (k0 + j > q) o[j] = 0.f;
  float4 lo = {o[0], o[1], o[2], o[3]};
  float4 hi = {o[4], o[5], o[6], o[7]};
  *reinterpret_cast<float4*>(arow) = lo;
  *reinterpret_cast<float4*>(arow + 4) = hi;
}

extern "C" void kernel_launch(void* const* d_in, const int* in_sizes, int n_in,
                              void* d_out, int out_size, void* d_ws, size_t ws_size,
                              hipStream_t stream) {
  const float* x  = (const float*)d_in[0];
  const float* Wq = (const float*)d_in[2];
  const float* bq = (const float*)d_in[3];
  const float* Wk = (const float*)d_in[4];
  const float* bk = (const float*)d_in[5];
  const float* Wv = (const float*)d_in[6];
  const float* bv = (const float*)d_in[7];
  const float* Wo = (const float*)d_in[8];
  const float* bo = (const float*)d_in[9];

  float* out_f = (float*)d_out;                    // [4,2048,1024]
  float* alpha = out_f + (size_t)MROWS * D_MODEL;  // [4,2048,2048]

  char* p = (char*)d_ws;
  __bf16* xb   = (__bf16*)p; p += (size_t)MROWS * D_MODEL * 2;      // reused as midb
  __bf16* wqb  = (__bf16*)p; p += (size_t)D_MODEL * D_MODEL * 2;    // wq|wk|wv|wo contiguous
  __bf16* wkb  = (__bf16*)p; p += (size_t)D_MODEL * D_MODEL * 2;
  __bf16* wvb  = (__bf16*)p; p += (size_t)D_MODEL * D_MODEL * 2;
  __bf16* wob  = (__bf16*)p; p += (size_t)D_MODEL * D_MODEL * 2;
  __bf16* qkv  = (__bf16*)p; p += (size_t)MROWS * QKV_LD * 2;       // 48 MB
  __bf16* vtb  = (__bf16*)p; p += (size_t)BATCH * D_MODEL * TSEQ * 2;
  float* lsum  = (float*)p;  p += (size_t)BATCH * NH * TSEQ * 4;
  float* bcat  = (float*)p;  p += 3072 * 4;
  __bf16* sbuf = (__bf16*)p;                                        // 35.7 MB per batch
  __bf16* midb = xb;

  // choose how many batches of scores fit in the remaining workspace
  size_t used = (size_t)((char*)sbuf - (char*)d_ws);
  size_t sb1 = SBATCH * 2;  // bytes per batch of scores
  int NB = 1;
  if (ws_size >= used + 4 * sb1) NB = 4;
  else if (ws_size >= used + 2 * sb1) NB = 2;
  size_t sstride = (NB > 1) ? SBATCH : 0;  // elems between batches in sbuf

  // 0) zero the atomic Lsum accumulator
  hipMemsetAsync(lsum, 0, (size_t)BATCH * NH * TSEQ * 4, stream);

  // 1) conversions + bias concat
  {
    int n4 = MROWS * D_MODEL / 4;
    cvt_f32_to_bf16<<<n4 / 256, 256, 0, stream>>>(x, xb, n4);
    int w4 = 4 * D_MODEL * D_MODEL / 4;
    cvt4_weights<<<w4 / 256, 256, 0, stream>>>(Wq, Wk, Wv, Wo, wqb);
    concat_bias<<<12, 256, 0, stream>>>(bq, bk, bv, bcat);
  }

  // 2) fused QKV projection: [8192x1024] @ [3072x1024]^T -> qkv[8192][3072]
  gemm128<true, false, false><<<dim3(QKV_LD / 128, MROWS / 128), 256, 0, stream>>>(
      xb, wqb, bcat, qkv, D_MODEL, QKV_LD, 0, 0, 0);

  // 3) V transpose (V = qkv cols 2048..3071)
  transpose_v<<<dim3(TSEQ / 64, D_MODEL / 64, BATCH), 256, 0, stream>>>(qkv + 2048, vtb);

  // 4) scores(+lsum) -> alpha, NB batches per launch pair
  for (int b0 = 0; b0 < BATCH; b0 += NB) {
    score_gemm<<<dim3(136, NH, NB), 256, 0, stream>>>(qkv, sbuf, lsum, b0, sstride);
    alpha_stream<<<dim3(TSEQ, NB), 256, 0, stream>>>(sbuf, lsum, alpha, b0, sstride);
  }

  // 5) Mid = alpha @ V
  gemm128<true, true, true><<<dim3(D_MODEL / 128, TSEQ / 128, BATCH), 256, 0, stream>>>(
      alpha, vtb, nullptr, midb, TSEQ, D_MODEL,
      (size_t)TSEQ * TSEQ, (size_t)D_MODEL * TSEQ, (size_t)TSEQ * D_MODEL);

  // 6) out = Mid @ Wo^T + bo
  gemm128<false, false, false><<<dim3(D_MODEL / 128, MROWS / 128), 256, 0, stream>>>(
      midb, wob, bo, out_f, D_MODEL, D_MODEL, 0, 0, 0);
}

// Round 9
// 360.571 us; speedup vs baseline: 1.4167x; 1.0076x over previous
//
#include <hip/hip_runtime.h>
#include <hip/hip_bf16.h>

#define D_MODEL 1024
#define NH 8
#define HD 128
#define BATCH 4
#define TSEQ 2048
#define MROWS (BATCH * TSEQ)  // 8192
#define QKV_LD 3072           // fused q|k|v row stride
#define SBAND 131072          // 8*128*128 elems per (qt-band unit)
#define SBATCH ((size_t)SBAND * 136)  // score elems per batch

typedef __attribute__((ext_vector_type(8))) __bf16 bf16x8;
typedef __attribute__((ext_vector_type(4))) __bf16 bf16x4;
typedef __attribute__((ext_vector_type(4))) float f32x4;
typedef __attribute__((ext_vector_type(8))) unsigned short u16x8;

#define SC2 0.1275174441680632f  // (1/sqrt(128)) * log2(e)

__device__ __forceinline__ void gload16(const void* g, void* lds) {
  __builtin_amdgcn_global_load_lds(
      (const __attribute__((address_space(1))) unsigned int*)g,
      (__attribute__((address_space(3))) unsigned int*)lds, 16, 0, 0);
}

// m204 bijective XCD swizzle of the linearized grid; returns remapped (x,y,z).
__device__ __forceinline__ dim3 swz_grid() {
  const int nx = gridDim.x, ny = gridDim.y;
  const int nwg = nx * ny * gridDim.z;
  int L = blockIdx.x + nx * (blockIdx.y + ny * blockIdx.z);
  const int q = nwg >> 3, r = nwg & 7;
  const int xcd = L & 7, idx = L >> 3;
  int t = (xcd < r ? xcd * (q + 1) : r * (q + 1) + (xcd - r) * q) + idx;
  dim3 o;
  o.x = t % nx; t /= nx;
  o.y = t % ny;
  o.z = t / ny;
  return o;
}

// ---------------- small conversion / setup kernels ----------------
__global__ __launch_bounds__(256) void cvt_f32_to_bf16(const float* __restrict__ in,
                                                       __bf16* __restrict__ out, int n4) {
  int i = blockIdx.x * 256 + threadIdx.x;
  if (i < n4) {
    float4 v = reinterpret_cast<const float4*>(in)[i];
    bf16x4 o;
    o[0] = (__bf16)v.x; o[1] = (__bf16)v.y; o[2] = (__bf16)v.z; o[3] = (__bf16)v.w;
    reinterpret_cast<bf16x4*>(out)[i] = o;
  }
}

__global__ __launch_bounds__(256) void cvt4_weights(const float* __restrict__ w0,
                                                    const float* __restrict__ w1,
                                                    const float* __restrict__ w2,
                                                    const float* __restrict__ w3,
                                                    __bf16* __restrict__ out) {
  const int per = D_MODEL * D_MODEL / 4;
  int i = blockIdx.x * 256 + threadIdx.x;
  int m = i / per, j = i - m * per;
  const float* src = (m == 0) ? w0 : (m == 1) ? w1 : (m == 2) ? w2 : w3;
  float4 v = reinterpret_cast<const float4*>(src)[j];
  bf16x4 o;
  o[0] = (__bf16)v.x; o[1] = (__bf16)v.y; o[2] = (__bf16)v.z; o[3] = (__bf16)v.w;
  reinterpret_cast<bf16x4*>(out)[i] = o;
}

__global__ __launch_bounds__(256) void concat_bias(const float* __restrict__ a,
                                                   const float* __restrict__ b,
                                                   const float* __restrict__ c,
                                                   float* __restrict__ o) {
  int i = blockIdx.x * 256 + threadIdx.x;
  if (i < 3072) o[i] = (i < 1024) ? a[i] : (i < 2048) ? b[i - 1024] : c[i - 2048];
}

// ---------------- generic 128x128 GEMM:  Y = A @ B^T (+bias), 2-phase dbuf ----
// BF16OUT epilogue: LDS-staged (16-seg XOR swizzle) -> coalesced 16B stores.
template <bool BF16OUT, bool CAUSAL, bool AFP32>
__global__ __launch_bounds__(256) void gemm128(const void* __restrict__ Aip,
                                               const __bf16* __restrict__ Bp,
                                               const float* __restrict__ bias,
                                               void* __restrict__ Yp, int K, int ldy,
                                               size_t sA, size_t sB, size_t sY) {
  __shared__ __bf16 sm[16384];  // As[2]|Bs[2] during K-loop; C-tile in epilogue
  __bf16* const As0 = sm;
  __bf16* const Bs0 = sm + 8192;
  const dim3 bi = swz_grid();
  const int tid = threadIdx.x;
  const int w = tid >> 6, l = tid & 63;
  const int lr = l & 15, lg = l >> 4;
  const int m0 = bi.y * 128, n0 = bi.x * 128;
  const int z = bi.z;
  const __bf16* Ab = AFP32 ? nullptr : (const __bf16*)Aip + z * sA;
  const float* Af = AFP32 ? (const float*)Aip + z * sA : nullptr;
  const __bf16* Bb = Bp + z * sB;
  const int wm = w >> 1, wn = w & 1;
  f32x4 acc[4][4] = {};
  const int Klim = CAUSAL ? (m0 + 128 < K ? m0 + 128 : K) : K;
  const int nt = Klim >> 5;

  auto stage = [&](int t, int buf) {
    const int k0 = t << 5;
    __bf16* As = As0 + buf * 4096;
    __bf16* Bs = Bs0 + buf * 4096;
    if constexpr (!AFP32) {
#pragma unroll
      for (int i = 0; i < 2; ++i) {
        int s = w * 128 + i * 64 + l;
        int row = s >> 2, scp = s & 3;
        int sc = scp ^ ((row >> 1) & 3);
        gload16(Ab + (size_t)(m0 + row) * K + k0 + sc * 8, (char*)As + s * 16);
      }
    } else {
#pragma unroll
      for (int i = 0; i < 2; ++i) {
        int s = w * 128 + i * 64 + l;
        int row = s >> 2, sc = s & 3;
        const float* src = Af + (size_t)(m0 + row) * K + k0 + sc * 8;
        float4 lo = *reinterpret_cast<const float4*>(src);
        float4 hi = *reinterpret_cast<const float4*>(src + 4);
        bf16x8 v;
        v[0] = (__bf16)lo.x; v[1] = (__bf16)lo.y; v[2] = (__bf16)lo.z; v[3] = (__bf16)lo.w;
        v[4] = (__bf16)hi.x; v[5] = (__bf16)hi.y; v[6] = (__bf16)hi.z; v[7] = (__bf16)hi.w;
        int p = row * 4 + (sc ^ ((row >> 1) & 3));
        *reinterpret_cast<bf16x8*>((char*)As + p * 16) = v;
      }
    }
#pragma unroll
    for (int i = 0; i < 2; ++i) {
      int s = w * 128 + i * 64 + l;
      int row = s >> 2, scp = s & 3;
      int sc = scp ^ ((row >> 1) & 3);
      gload16(Bb + (size_t)(n0 + row) * K + k0 + sc * 8, (char*)Bs + s * 16);
    }
  };

  stage(0, 0);
  __syncthreads();
  int cur = 0;
  for (int t = 0; t < nt; ++t) {
    if (t + 1 < nt) stage(t + 1, cur ^ 1);
    bf16x8 af[4], bf[4];
#pragma unroll
    for (int f = 0; f < 4; ++f) {
      int ar = wm * 64 + f * 16 + lr;
      af[f] = *reinterpret_cast<const bf16x8*>((const char*)(As0 + cur * 4096) + ar * 64 +
                                               ((lg ^ ((ar >> 1) & 3)) * 16));
      int br = wn * 64 + f * 16 + lr;
      bf[f] = *reinterpret_cast<const bf16x8*>((const char*)(Bs0 + cur * 4096) + br * 64 +
                                               ((lg ^ ((br >> 1) & 3)) * 16));
    }
#pragma unroll
    for (int mf = 0; mf < 4; ++mf)
#pragma unroll
      for (int nf = 0; nf < 4; ++nf)
        acc[mf][nf] = __builtin_amdgcn_mfma_f32_16x16x32_bf16(af[mf], bf[nf], acc[mf][nf], 0, 0, 0);
    __syncthreads();
    cur ^= 1;
  }

  if constexpr (BF16OUT) {
    float bv[4];
#pragma unroll
    for (int nf = 0; nf < 4; ++nf) bv[nf] = bias ? bias[n0 + wn * 64 + nf * 16 + lr] : 0.f;
#pragma unroll
    for (int mf = 0; mf < 4; ++mf)
#pragma unroll
      for (int r = 0; r < 4; ++r) {
        int row = wm * 64 + mf * 16 + lg * 4 + r;
#pragma unroll
        for (int nf = 0; nf < 4; ++nf) {
          int col = wn * 64 + nf * 16 + lr;
          int pseg = (col >> 3) ^ (row & 15);
          sm[row * 128 + pseg * 8 + (col & 7)] = (__bf16)(acc[mf][nf][r] + bv[nf]);
        }
      }
    __syncthreads();
    __bf16* Yb = (__bf16*)Yp + z * sY;
#pragma unroll
    for (int i = 0; i < 8; ++i) {
      int s = i * 256 + tid;
      int row = s >> 4, pseg = s & 15;
      int lseg = pseg ^ (row & 15);
      bf16x8 v = *reinterpret_cast<bf16x8*>(sm + row * 128 + pseg * 8);
      *reinterpret_cast<bf16x8*>(&Yb[(size_t)(m0 + row) * ldy + n0 + lseg * 8]) = v;
    }
  } else {
#pragma unroll
    for (int mf = 0; mf < 4; ++mf)
#pragma unroll
      for (int nf = 0; nf < 4; ++nf)
#pragma unroll
        for (int r = 0; r < 4; ++r) {
          int grow = m0 + wm * 64 + mf * 16 + lg * 4 + r;
          int gcol = n0 + wn * 64 + nf * 16 + lr;
          float v = acc[mf][nf][r];
          if (bias) v += bias[gcol];
          ((float*)Yp + z * sY)[(size_t)grow * ldy + gcol] = v;
        }
  }
}

// ---------------- V[b][t][d] (ld=QKV_LD) -> Vt[b][d][t] ----------------
__global__ __launch_bounds__(256) void transpose_v(const __bf16* __restrict__ V,
                                                   __bf16* __restrict__ Vt) {
  __shared__ unsigned short tile[64 * 72];
  const int b = blockIdx.z;
  const int t0 = blockIdx.x * 64, d0 = blockIdx.y * 64;
  const int tid = threadIdx.x;
#pragma unroll
  for (int i = 0; i < 2; ++i) {
    int s = i * 256 + tid;
    int r = s >> 3, c8 = s & 7;
    u16x8 v = *reinterpret_cast<const u16x8*>(V + ((size_t)b * TSEQ + t0 + r) * QKV_LD + d0 + c8 * 8);
    *reinterpret_cast<u16x8*>(&tile[r * 72 + c8 * 8]) = v;
  }
  __syncthreads();
#pragma unroll
  for (int i = 0; i < 2; ++i) {
    int s = i * 256 + tid;
    int dr = s >> 3, t8 = s & 7;
    u16x8 o;
#pragma unroll
    for (int j = 0; j < 8; ++j) o[j] = tile[(t8 * 8 + j) * 72 + dr];
    *reinterpret_cast<u16x8*>(Vt + ((size_t)b * D_MODEL + d0 + dr) * TSEQ + t0 + t8 * 8) = o;
  }
}

// ---------------- score GEMM: E=exp2(S*SC2) tiles (bf16) + Lsum atomics -------
// Grid (136 causal tiles, 8 heads, NB batches). 256 thr, 128x128 tile, K=128.
// Epilogue: e staged to LDS (XOR swizzle) -> coalesced 16B stores; fp32 lsum.
__global__ __launch_bounds__(256) void score_gemm(const __bf16* __restrict__ QKV,
                                                  __bf16* __restrict__ S,
                                                  float* __restrict__ lsum,
                                                  int b0, size_t sstride) {
  __shared__ __bf16 sm[16384];
  __bf16* const As0 = sm;
  __bf16* const Bs0 = sm + 8192;
  const dim3 bi = swz_grid();
  const int tid = threadIdx.x;
  const int w = tid >> 6, l = tid & 63;
  const int lr = l & 15, lg = l >> 4;
  const int wm = w >> 1, wn = w & 1;
  const int idx = bi.x;
  const int h = bi.y;
  const int zz = bi.z;
  const int b = b0 + zz;
  int qt = (int)((sqrtf(8.f * (float)idx + 1.f) - 1.f) * 0.5f);
  while ((qt + 1) * (qt + 2) / 2 <= idx) ++qt;
  while (qt * (qt + 1) / 2 > idx) --qt;
  const int kt = idx - qt * (qt + 1) / 2;
  const int q0 = qt * 128, k0 = kt * 128;
  const int kext = (qt + 1) * 128;
  const bool diag = (kt == qt);

  const __bf16* Ab = QKV + (size_t)(b * TSEQ + q0) * QKV_LD + h * HD;         // Q
  const __bf16* Bb = QKV + (size_t)(b * TSEQ + k0) * QKV_LD + 1024 + h * HD;  // K

  auto stage = [&](int t, int buf) {
    __bf16* As = As0 + buf * 4096;
    __bf16* Bs = Bs0 + buf * 4096;
#pragma unroll
    for (int i = 0; i < 2; ++i) {
      int s = w * 128 + i * 64 + l;
      int row = s >> 2, scp = s & 3;
      int sc = scp ^ ((row >> 1) & 3);
      gload16(Ab + (size_t)row * QKV_LD + t * 32 + sc * 8, (char*)As + s * 16);
    }
#pragma unroll
    for (int i = 0; i < 2; ++i) {
      int s = w * 128 + i * 64 + l;
      int row = s >> 2, scp = s & 3;
      int sc = scp ^ ((row >> 1) & 3);
      gload16(Bb + (size_t)row * QKV_LD + t * 32 + sc * 8, (char*)Bs + s * 16);
    }
  };

  f32x4 acc[4][4] = {};
  stage(0, 0);
  __syncthreads();
  int cur = 0;
#pragma unroll
  for (int t = 0; t < 4; ++t) {
    if (t < 3) stage(t + 1, cur ^ 1);
    bf16x8 af[4], bf[4];
#pragma unroll
    for (int f = 0; f < 4; ++f) {
      int ar = wm * 64 + f * 16 + lr;
      af[f] = *reinterpret_cast<const bf16x8*>((const char*)(As0 + cur * 4096) + ar * 64 +
                                               ((lg ^ ((ar >> 1) & 3)) * 16));
      int br = wn * 64 + f * 16 + lr;
      bf[f] = *reinterpret_cast<const bf16x8*>((const char*)(Bs0 + cur * 4096) + br * 64 +
                                               ((lg ^ ((br >> 1) & 3)) * 16));
    }
#pragma unroll
    for (int mf = 0; mf < 4; ++mf)
#pragma unroll
      for (int nf = 0; nf < 4; ++nf)
        acc[mf][nf] = __builtin_amdgcn_mfma_f32_16x16x32_bf16(af[mf], bf[nf], acc[mf][nf], 0, 0, 0);
    __syncthreads();
    cur ^= 1;
  }

  // epilogue: e = exp2(s*SC2) -> LDS (swizzled) + causal fp32 row-sum
  float ls[4][4] = {};
#pragma unroll
  for (int mf = 0; mf < 4; ++mf)
#pragma unroll
    for (int r = 0; r < 4; ++r) {
      int row = wm * 64 + mf * 16 + lg * 4 + r;
#pragma unroll
      for (int nf = 0; nf < 4; ++nf) {
        int col = wn * 64 + nf * 16 + lr;
        float ev = exp2f(acc[mf][nf][r] * SC2);
        int pseg = (col >> 3) ^ (row & 15);
        sm[row * 128 + pseg * 8 + (col & 7)] = (__bf16)ev;
        if (!diag || col <= row) ls[mf][r] += ev;
      }
    }
#pragma unroll
  for (int m = 1; m < 16; m <<= 1)
#pragma unroll
    for (int mf = 0; mf < 4; ++mf)
#pragma unroll
      for (int r = 0; r < 4; ++r) ls[mf][r] += __shfl_xor(ls[mf][r], m, 64);
  if (lr == 0) {
#pragma unroll
    for (int mf = 0; mf < 4; ++mf)
#pragma unroll
      for (int r = 0; r < 4; ++r)
        atomicAdd(&lsum[((size_t)(b * NH + h)) * TSEQ + q0 + wm * 64 + mf * 16 + lg * 4 + r],
                  ls[mf][r]);
  }
  __syncthreads();
  __bf16* Sb = S + zz * sstride + (size_t)SBAND * ((qt * (qt + 1)) >> 1) +
               (size_t)h * 128 * kext + k0;
#pragma unroll
  for (int i = 0; i < 8; ++i) {
    int s = i * 256 + tid;
    int row = s >> 4, pseg = s & 15;
    int lseg = pseg ^ (row & 15);
    bf16x8 v = *reinterpret_cast<bf16x8*>(sm + row * 128 + pseg * 8);
    *reinterpret_cast<bf16x8*>(&Sb[(size_t)row * kext + lseg * 8]) = v;
  }
}

// ---------------- alpha streaming: alpha[q][k] = sum_h e_h/(8*Lsum_h) ---------
// Grid (TSEQ, NB). One block per q row (256 thr x 8 k each). No transcendentals.
__global__ __launch_bounds__(256) void alpha_stream(const __bf16* __restrict__ S,
                                                    const float* __restrict__ lsum,
                                                    float* __restrict__ alpha,
                                                    int b0, size_t sstride) {
  const int q = blockIdx.x;
  const int zz = blockIdx.y;
  const int b = b0 + zz;
  const int qt = q >> 7;
  const int kext = (qt + 1) * 128;
  const int k0 = threadIdx.x * 8;
  float* arow = alpha + ((size_t)(b * TSEQ + q)) * TSEQ + k0;
  if (k0 >= kext) {
    float4 zzf = {0.f, 0.f, 0.f, 0.f};
    *reinterpret_cast<float4*>(arow) = zzf;
    *reinterpret_cast<float4*>(arow + 4) = zzf;
    return;
  }
  const __bf16* Sb = S + zz * sstride + (size_t)SBAND * ((qt * (qt + 1)) >> 1) +
                     (size_t)(q & 127) * kext + k0;
  const size_t hstride = (size_t)128 * kext;
  float o[8] = {};
#pragma unroll
  for (int h = 0; h < NH; ++h) {
    float li = 1.0f / (8.0f * lsum[((size_t)(b * NH + h)) * TSEQ + q]);
    bf16x8 s8 = *reinterpret_cast<const bf16x8*>(Sb + h * hstride);
#pragma unroll
    for (int j = 0; j < 8; ++j) o[j] += (float)s8[j] * li;
  }
#pragma unroll
  for (int j = 0; j < 8; ++j)
    if (k0 + j > q) o[j] = 0.f;
  float4 lo = {o[0], o[1], o[2], o[3]};
  float4 hi = {o[4], o[5], o[6], o[7]};
  *reinterpret_cast<float4*>(arow) = lo;
  *reinterpret_cast<float4*>(arow + 4) = hi;
}

extern "C" void kernel_launch(void* const* d_in, const int* in_sizes, int n_in,
                              void* d_out, int out_size, void* d_ws, size_t ws_size,
                              hipStream_t stream) {
  const float* x  = (const float*)d_in[0];
  const float* Wq = (const float*)d_in[2];
  const float* bq = (const float*)d_in[3];
  const float* Wk = (const float*)d_in[4];
  const float* bk = (const float*)d_in[5];
  const float* Wv = (const float*)d_in[6];
  const float* bv = (const float*)d_in[7];
  const float* Wo = (const float*)d_in[8];
  const float* bo = (const float*)d_in[9];

  float* out_f = (float*)d_out;                    // [4,2048,1024]
  float* alpha = out_f + (size_t)MROWS * D_MODEL;  // [4,2048,2048]

  char* p = (char*)d_ws;
  __bf16* xb   = (__bf16*)p; p += (size_t)MROWS * D_MODEL * 2;      // reused as midb
  __bf16* wqb  = (__bf16*)p; p += (size_t)D_MODEL * D_MODEL * 2;    // wq|wk|wv|wo contiguous
  __bf16* wkb  = (__bf16*)p; p += (size_t)D_MODEL * D_MODEL * 2;
  __bf16* wvb  = (__bf16*)p; p += (size_t)D_MODEL * D_MODEL * 2;
  __bf16* wob  = (__bf16*)p; p += (size_t)D_MODEL * D_MODEL * 2;
  __bf16* qkv  = (__bf16*)p; p += (size_t)MROWS * QKV_LD * 2;       // 48 MB
  __bf16* vtb  = (__bf16*)p; p += (size_t)BATCH * D_MODEL * TSEQ * 2;
  float* lsum  = (float*)p;  p += (size_t)BATCH * NH * TSEQ * 4;
  float* bcat  = (float*)p;  p += 3072 * 4;
  __bf16* sbuf = (__bf16*)p;                                        // 35.7 MB per batch
  __bf16* midb = xb;

  // choose how many batches of scores fit in the remaining workspace
  size_t used = (size_t)((char*)sbuf - (char*)d_ws);
  size_t sb1 = SBATCH * 2;  // bytes per batch of scores
  int NB = 1;
  if (ws_size >= used + 4 * sb1) NB = 4;
  else if (ws_size >= used + 2 * sb1) NB = 2;
  size_t sstride = (NB > 1) ? SBATCH : 0;  // elems between batches in sbuf

  // 0) zero the atomic Lsum accumulator
  hipMemsetAsync(lsum, 0, (size_t)BATCH * NH * TSEQ * 4, stream);

  // 1) conversions + bias concat
  {
    int n4 = MROWS * D_MODEL / 4;
    cvt_f32_to_bf16<<<n4 / 256, 256, 0, stream>>>(x, xb, n4);
    int w4 = 4 * D_MODEL * D_MODEL / 4;
    cvt4_weights<<<w4 / 256, 256, 0, stream>>>(Wq, Wk, Wv, Wo, wqb);
    concat_bias<<<12, 256, 0, stream>>>(bq, bk, bv, bcat);
  }

  // 2) fused QKV projection: [8192x1024] @ [3072x1024]^T -> qkv[8192][3072]
  gemm128<true, false, false><<<dim3(QKV_LD / 128, MROWS / 128), 256, 0, stream>>>(
      xb, wqb, bcat, qkv, D_MODEL, QKV_LD, 0, 0, 0);

  // 3) V transpose (V = qkv cols 2048..3071)
  transpose_v<<<dim3(TSEQ / 64, D_MODEL / 64, BATCH), 256, 0, stream>>>(qkv + 2048, vtb);

  // 4) scores(e,+lsum) -> alpha, NB batches per launch pair
  for (int b0 = 0; b0 < BATCH; b0 += NB) {
    score_gemm<<<dim3(136, NH, NB), 256, 0, stream>>>(qkv, sbuf, lsum, b0, sstride);
    alpha_stream<<<dim3(TSEQ, NB), 256, 0, stream>>>(sbuf, lsum, alpha, b0, sstride);
  }

  // 5) Mid = alpha @ V
  gemm128<true, true, true><<<dim3(D_MODEL / 128, TSEQ / 128, BATCH), 256, 0, stream>>>(
      alpha, vtb, nullptr, midb, TSEQ, D_MODEL,
      (size_t)TSEQ * TSEQ, (size_t)D_MODEL * TSEQ, (size_t)TSEQ * D_MODEL);

  // 6) out = Mid @ Wo^T + bo
  gemm128<false, false, false><<<dim3(D_MODEL / 128, MROWS / 128), 256, 0, stream>>>(
      midb, wob, bo, out_f, D_MODEL, D_MODEL, 0, 0, 0);
}